// Round 17
// baseline (381.554 us; speedup 1.0000x reference)
//
#include <hip/hip_runtime.h>
#include <math.h>

#if !__has_builtin(__builtin_amdgcn_cvt_pk_fp8_f32)
#include <hip/hip_fp8.h>
#endif

typedef __attribute__((ext_vector_type(8))) short short8;
typedef __attribute__((ext_vector_type(4))) float f32x4;
typedef __attribute__((ext_vector_type(16))) float f32x16;
typedef unsigned char u8;
typedef unsigned short u16;
typedef unsigned int u32;
typedef __attribute__((ext_vector_type(2))) u32 u32x2;
typedef __attribute__((ext_vector_type(4))) u32 u32x4;
typedef __attribute__((ext_vector_type(8))) int i32x8;
typedef unsigned long long u64;

static constexpr int E = 1024, H = 16, LQ = 1024, LC = 512, Bn = 4, FF = 4096;
static constexpr int NTOK = Bn * LQ;   // 4096
static constexpr int NCTX = Bn * LC;   // 2048

// Q pre-scale: 1/sqrt(64) * log2(e)  (softmax runs in exp2 domain)
#define QSCALE 0.1803368801111244f
#define DEFER_THR 11.5f
#define AOSCL 16.0f   // attention-output fp8 scale

// ---------------- workspace layout (bytes) ----------------
static constexpr size_t OFF_TCOS   = 0;                                    // 1024*32 f32
static constexpr size_t OFF_TSIN   = OFF_TCOS + (size_t)LQ*32*4;
static constexpr size_t OFF_BSAQKV = OFF_TSIN + (size_t)LQ*32*4;           // 3072 f32 (+ca_k/v bias after)
static constexpr size_t OFF_BCAKV  = OFF_BSAQKV + 16384;                   // 2048 f32
// fp8 weight region (contiguous, 18 MB)
static constexpr size_t OFF_W8     = OFF_BCAKV + 16384;
static constexpr size_t OFF_W8QKV  = OFF_W8;                               // [3072][1024]
static constexpr size_t OFF_W8SAP  = OFF_W8QKV  + (size_t)3*1048576;       // [1024][1024]
static constexpr size_t OFF_W8CAQ  = OFF_W8SAP  + (size_t)1*1048576;
static constexpr size_t OFF_W8CAKV = OFF_W8CAQ  + (size_t)1*1048576;       // [2048][1024]
static constexpr size_t OFF_W8CAP  = OFF_W8CAKV + (size_t)2*1048576;
static constexpr size_t OFF_W8FC1  = OFF_W8CAP  + (size_t)1*1048576;       // [4096][1024]
static constexpr size_t OFF_W8FC2  = OFF_W8FC1  + (size_t)4*1048576;       // [1024][4096]
static constexpr size_t OFF_CTX8   = OFF_W8FC2  + (size_t)4*1048576;       // [2048][1024] fp8
// activation region
static constexpr size_t OFF_CTXB   = OFF_W8 + (size_t)30*1048576 + (size_t)2048*1024*2; // (dead)
static constexpr size_t OFF_H      = OFF_CTXB   + (size_t)2048*1024*2;     // [4096][1024] fp8 ln out
static constexpr size_t OFF_QKV    = OFF_H      + (size_t)4096*1024*2;     // [4096][3072] bf16
static constexpr size_t OFF_CAQ    = OFF_QKV;                              // [4096][1024]
static constexpr size_t OFF_CAKV   = OFF_QKV + (size_t)4096*1024*2;        // [2048][2048]
static constexpr size_t OFF_QR     = OFF_QKV + (size_t)4096*3072*2;        // [B,H,LQ,64]
static constexpr size_t OFF_KR     = OFF_QR  + (size_t)4096*1024*2;        // [B,H,Lk,64]
static constexpr size_t OFF_VT     = OFF_KR  + (size_t)4096*1024*2;        // [B,H,64,Lk]
static constexpr size_t OFF_AO     = OFF_VT  + (size_t)4096*1024*2;        // [4096][1024] fp8
static constexpr size_t OFF_U      = OFF_QKV;                              // fc1 out fp8 reuses QKV
static constexpr size_t WS_NEED    = OFF_AO + (size_t)4096*1024*2;         // ~105 MB

// ---------------- helpers ----------------
static __device__ __forceinline__ float bf2f(u16 u) {
  union { u32 i; float f; } un; un.i = ((u32)u) << 16; return un.f;
}
static __device__ __forceinline__ u16 f2bf(float f) {  // RNE
  union { float f; u32 u; } un; un.f = f;
  u32 u = un.u;
  return (u16)((u + 0x7FFFu + ((u >> 16) & 1u)) >> 16);
}
static __device__ __forceinline__ u64 pack4(u16 a, u16 b, u16 c, u16 d) {
  return (u64)a | ((u64)b << 16) | ((u64)c << 32) | ((u64)d << 48);
}
static __device__ __forceinline__ f32x16 mfma32(short8 a, short8 b, f32x16 c) {
  return __builtin_amdgcn_mfma_f32_32x32x16_bf16(a, b, c, 0, 0, 0);
}
static __device__ __forceinline__ void gload_lds16(void* lds, const void* g) {
  __builtin_amdgcn_global_load_lds(
      (const __attribute__((address_space(1))) void*)g,
      (__attribute__((address_space(3))) void*)lds, 16, 0, 0);
}
// gelu(x) = 0.5x(1+tanh(z)) = x*e/(e+1), e=exp(2*0.79788456(x+0.044715x^3)).
static __device__ __forceinline__ float gelu_tanh(float x) {
  float z2 = 1.5957691216057308f * (x + 0.044715f * x * x * x);
  float e = __expf(z2);
  float r = __builtin_amdgcn_rcpf(e + 1.0f);
  return x - x * r;   // x*(1 - 1/(e+1)) = x*e/(e+1)
}
static __device__ __forceinline__ u32 cvtpk_bf16(float lo, float hi) {
  u32 r;
  asm("v_cvt_pk_bf16_f32 %0, %1, %2" : "=v"(r) : "v"(lo), "v"(hi));
  return r;
}
// fp32 -> OCP e4m3 (saturating)
static __device__ __forceinline__ u32 pack_fp8x4(float a, float b, float c, float d) {
#if __has_builtin(__builtin_amdgcn_cvt_pk_fp8_f32)
  u32 r = (u32)__builtin_amdgcn_cvt_pk_fp8_f32(a, b, 0, false);
  r = (u32)__builtin_amdgcn_cvt_pk_fp8_f32(c, d, (int)r, true);
  return r;
#else
  __hip_fp8_e4m3 qa(a), qb(b), qc(c), qd(d);
  return (u32)qa.__x | ((u32)qb.__x << 8) | ((u32)qc.__x << 16) | ((u32)qd.__x << 24);
#endif
}
static __device__ __forceinline__ u8 fp8b(float f) {
#if __has_builtin(__builtin_amdgcn_cvt_pk_fp8_f32)
  return (u8)((u32)__builtin_amdgcn_cvt_pk_fp8_f32(f, f, 0, false) & 0xFFu);
#else
  __hip_fp8_e4m3 t(f); return t.__x;
#endif
}

// ---------------- small kernels ----------------
__global__ __launch_bounds__(256) void build_tab(float* __restrict__ ct, float* __restrict__ st) {
  int idx = blockIdx.x * 256 + threadIdx.x;           // 1024*32 entries
  int pos = idx >> 5, i = idx & 31;
  float inv = powf(10000.f, -(float)i * (1.f / 32.f));
  float a = (float)pos * inv;
  ct[idx] = cosf(a);
  st[idx] = sinf(a);
}

// ALL weights + ctx -> fp8 e4m3 (weights x256, ctx x16), 18 segments of 1M elems.
struct CvtF8 { const float* s[10]; };
__global__ __launch_bounds__(256) void cvt_fp8c(CvtF8 a, const float* __restrict__ ctx,
                                                u8* __restrict__ dst) {
  u32 gid = blockIdx.x * 256 + threadIdx.x;   // 0 .. 18*262144-1, 4 elems each
  u32 seg = gid >> 18, off = gid & 262143u;
  const float* s;
  float scl = 256.f;
  if (seg < 8)       s = a.s[seg];
  else if (seg < 12) s = a.s[8] + (size_t)(seg - 8) * 1048576;
  else if (seg < 16) s = a.s[9] + (size_t)(seg - 12) * 1048576;
  else             { s = ctx + (size_t)(seg - 16) * 1048576; scl = 16.f; }
  float4 v = *(const float4*)(s + (size_t)off * 4);
  *(u32*)(dst + (size_t)seg * 1048576 + (size_t)off * 4) =
      pack_fp8x4(v.x * scl, v.y * scl, v.z * scl, v.w * scl);
}

// fused bias copies
struct Cp5 { const float* s[5]; };
__global__ __launch_bounds__(256) void copy5(Cp5 a, float* __restrict__ dst) {
  int gid = blockIdx.x * 256 + threadIdx.x;   // 0..5119
  int s = gid >> 10, off = gid & 1023;
  int doff = (s < 3) ? s * 1024 : 4096 + (s - 3) * 1024;
  dst[doff + off] = a.s[s][off];
}

// out[row][c] += gate[c]*bias[c]
__global__ __launch_bounds__(256) void init_bias_gate(float* __restrict__ out, const float* __restrict__ bias,
                                                      const float* __restrict__ gate) {
  int i = (blockIdx.x * 256 + threadIdx.x) * 4;
  int c = i & 1023;
  float4 o = *(float4*)(out + i);
  o.x += gate[c] * bias[c];
  o.y += gate[c + 1] * bias[c + 1];
  o.z += gate[c + 2] * bias[c + 2];
  o.w += gate[c + 3] * bias[c + 3];
  *(float4*)(out + i) = o;
}

// LN -> fp8 e4m3 scaled x16
__global__ __launch_bounds__(256) void ln_fp8(const float* __restrict__ x, const float* __restrict__ w,
                                              const float* __restrict__ b, u8* __restrict__ out) {
  __shared__ float red[4];
  int row = blockIdx.x, tid = threadIdx.x;
  const float* xr = x + (size_t)row * 1024;
  float4 v = ((const float4*)xr)[tid];
  float s = v.x + v.y + v.z + v.w;
#pragma unroll
  for (int off = 32; off; off >>= 1) s += __shfl_xor(s, off);
  if ((tid & 63) == 0) red[tid >> 6] = s;
  __syncthreads();
  float mean = (red[0] + red[1] + red[2] + red[3]) * (1.f / 1024.f);
  float dx = v.x - mean, dy = v.y - mean, dz = v.z - mean, dw = v.w - mean;
  float sq = dx * dx + dy * dy + dz * dz + dw * dw;
#pragma unroll
  for (int off = 32; off; off >>= 1) sq += __shfl_xor(sq, off);
  __syncthreads();
  if ((tid & 63) == 0) red[tid >> 6] = sq;
  __syncthreads();
  float var = (red[0] + red[1] + red[2] + red[3]) * (1.f / 1024.f);
  float rstd = rsqrtf(var + 1e-6f);
  float4 wv = ((const float4*)w)[tid];
  float4 bv = ((const float4*)b)[tid];
  u32 pk = pack_fp8x4((dx * rstd * wv.x + bv.x) * 16.f, (dy * rstd * wv.y + bv.y) * 16.f,
                      (dz * rstd * wv.z + bv.z) * 16.f, (dw * rstd * wv.w + bv.w) * 16.f);
  *(u32*)(out + (size_t)row * 1024 + tid * 4) = pk;
}

// Fused RoPE (Q,K only)
struct RopeJob { const u16* src; u16* dst; int ld, col0, Lper, T; float scale; };
struct Rope2 { RopeJob j[2]; };
__global__ __launch_bounds__(128) void rope2(Rope2 a, const float* __restrict__ cosT,
                                             const float* __restrict__ sinT) {
  RopeJob jb = a.j[blockIdx.y];
  int t = blockIdx.x;
  if (t >= jb.T) return;
  int b = t / jb.Lper, l = t - b * jb.Lper;
  int tid = threadIdx.x;
  int e0 = tid * 8;
  int h = e0 >> 6, d0 = e0 & 63;
  short8 vv = *(const short8*)(jb.src + (size_t)t * jb.ld + jb.col0 + e0);
  short8 ov;
#pragma unroll
  for (int j = 0; j < 4; ++j) {
    float x1 = bf2f((u16)vv[2 * j]);
    float x2 = bf2f((u16)vv[2 * j + 1]);
    int i = (d0 >> 1) + j;
    float c = cosT[l * 32 + i], s = sinT[l * 32 + i];
    ov[2 * j]     = (short)f2bf((x1 * c - x2 * s) * jb.scale);
    ov[2 * j + 1] = (short)f2bf((x1 * s + x2 * c) * jb.scale);
  }
  *(short8*)(jb.dst + (((size_t)b * H + h) * jb.Lper + l) * 64 + d0) = ov;
}

// V transpose with COALESCED writes
__global__ __launch_bounds__(256) void vtrans(const u16* __restrict__ src, int ld, int col0,
                                              u16* __restrict__ dst, int Lper) {
  __shared__ u16 tile[64][72];
  int bh = blockIdx.y;
  int b = bh >> 4, h = bh & 15;
  int l0 = blockIdx.x * 64;
  int tid = threadIdx.x;
#pragma unroll
  for (int j = 0; j < 2; ++j) {
    int c = tid + j * 256;
    int i = c >> 3, d0 = (c & 7) * 8;
    short8 v = *(const short8*)(src + (size_t)(b * Lper + l0 + i) * ld + col0 + h * 64 + d0);
    *(short8*)(&tile[i][d0]) = v;
  }
  __syncthreads();
#pragma unroll
  for (int j = 0; j < 2; ++j) {
    int c = tid + j * 256;
    int d = c >> 3, lc = (c & 7) * 8;
    short8 v;
#pragma unroll
    for (int k = 0; k < 8; ++k) v[k] = (short)tile[lc + k][d];
    *(short8*)(dst + (((size_t)bh) * 64 + d) * Lper + l0 + lc) = v;
  }
}

// ---------------- fp8 MX GEMM: C = (A/16) @ (W/256)^T -> acc/4096 ----------------
// 128x128 tile, BK=128, 256 threads (2x2 waves of 64x64 = 4x4 16x16-frags).
// A read DIRECTLY from global/L2 (no LDS staging); B double-buffered in 32 KiB
// LDS -> 3 blocks/CU co-resident (12 waves/CU) hide the halved drain + L2 lat.
enum { E8_BF16 = 0, E8_GELU = 1, E8_ATOMIC = 2, E8_RESID = 3 };

template <int EPI>
__global__ __launch_bounds__(256, 3) void gemm8(const u8* __restrict__ A, const u8* __restrict__ W,
                                                const float* __restrict__ bias, u16* outb16,
                                                u8* outb8, float* outf, const float* res,
                                                const float* __restrict__ gate,
                                                int M, int N, int K, int kchunks) {
  __shared__ u8 Bs[2][128 * 128];   // 32 KiB total

  int nwg = gridDim.x * gridDim.y;
  int bid = blockIdx.y * gridDim.x + blockIdx.x;
  int cpx = nwg >> 3;
  int swz = (bid & 7) * cpx + (bid >> 3);
  int bx = swz % gridDim.x, by = swz / gridDim.x;
  int row0 = by * 128, col0 = bx * 128;

  const int Kc = K / kchunks;
  const int kbase = blockIdx.z * Kc;

  int tid = threadIdx.x;
  int lane = tid & 63, wid = tid >> 6;
  int wr = wid >> 1, wc = wid & 1;      // 2x2 waves, each owns 64x64
  int lr = lane & 15, lg = lane >> 4;

  // B staging: tile = 128 rows x 128 B = 1024 chunks of 16 B; 4 per thread.
  u32 boff[4];
  int ldso[4];
#pragma unroll
  for (int j = 0; j < 4; ++j) {
    int q = tid + j * 256;
    int r = q >> 3, p = q & 7, sp = p ^ (r & 7);
    boff[j] = (u32)(col0 + r) * (u32)K + sp * 16;
    ldso[j] = q * 16;
  }
  // A direct-read row pointers (per m-fragment): 32 contiguous bytes/lane.
  const u8* arow[4];
#pragma unroll
  for (int m = 0; m < 4; ++m)
    arow[m] = A + (size_t)(row0 + wr * 64 + m * 16 + lr) * K + lg * 32 + kbase;

  f32x4 acc[4][4] = {};
  const int nkt = Kc >> 7;              // BK = 128

  auto rdA = [&](int m, int kb, i32x8& f) {
    const u8* rp = arow[m] + kb;
    u32x4 lo = *(const u32x4*)(rp);
    u32x4 hh = *(const u32x4*)(rp + 16);
    i32x8 v;
    v[0] = (int)lo[0]; v[1] = (int)lo[1]; v[2] = (int)lo[2]; v[3] = (int)lo[3];
    v[4] = (int)hh[0]; v[5] = (int)hh[1]; v[6] = (int)hh[2]; v[7] = (int)hh[3];
    f = v;
  };
  auto rdB = [&](const u8* base, int r, i32x8& f) {
    const u8* rp = base + r * 128;
    int ck = lg * 2;
    u32x4 lo = *(const u32x4*)(rp + ((ck) ^ (r & 7)) * 16);
    u32x4 hh = *(const u32x4*)(rp + ((ck + 1) ^ (r & 7)) * 16);
    i32x8 v;
    v[0] = (int)lo[0]; v[1] = (int)lo[1]; v[2] = (int)lo[2]; v[3] = (int)lo[3];
    v[4] = (int)hh[0]; v[5] = (int)hh[1]; v[6] = (int)hh[2]; v[7] = (int)hh[3];
    f = v;
  };

  // prologue: stage B tile 0
#pragma unroll
  for (int j = 0; j < 4; ++j) gload_lds16(&Bs[0][ldso[j]], W + boff[j] + kbase);
  __syncthreads();

  for (int kt = 0; kt < nkt; ++kt) {
    int cur = kt & 1;
    if (kt + 1 < nkt) {
      int k0 = kbase + ((kt + 1) << 7);
#pragma unroll
      for (int j = 0; j < 4; ++j) gload_lds16(&Bs[cur ^ 1][ldso[j]], W + boff[j] + k0);
    }
    i32x8 a[4], b[4];
#pragma unroll
    for (int m = 0; m < 4; ++m) rdA(m, kt << 7, a[m]);
#pragma unroll
    for (int n = 0; n < 4; ++n) rdB(&Bs[cur][0], wc * 64 + n * 16 + lr, b[n]);
    __builtin_amdgcn_s_setprio(1);
#pragma unroll
    for (int m = 0; m < 4; ++m)
#pragma unroll
      for (int n = 0; n < 4; ++n)
        acc[m][n] = __builtin_amdgcn_mfma_scale_f32_16x16x128_f8f6f4(
            a[m], b[n], acc[m][n], 0, 0, 0, 0x7F7F7F7F, 0, 0x7F7F7F7F);
    __builtin_amdgcn_s_setprio(0);
    __syncthreads();
  }

  // epilogue: C layout col=lane&15, row=(lane>>4)*4+i; Bs is dead -> staging buf
  constexpr float SCL = 1.f / 4096.f;   // undo x16 (act) * x256 (weights)
  if (EPI == E8_BF16) {
    u16* Ct = (u16*)&Bs[0][0];          // [128][128] u16 = 32 KiB
#pragma unroll
    for (int n = 0; n < 4; ++n) {
      int cl = wc * 64 + n * 16 + lr;
      float bv = bias[col0 + cl];
#pragma unroll
      for (int m = 0; m < 4; ++m) {
#pragma unroll
        for (int i = 0; i < 4; ++i) {
          int rl = wr * 64 + m * 16 + lg * 4 + i;
          Ct[rl * 128 + cl] = f2bf(acc[m][n][i] * SCL + bv);
        }
      }
    }
    __syncthreads();
#pragma unroll
    for (int j = 0; j < 8; ++j) {
      u32 q = (u32)tid + j * 256;
      u32 r = q >> 4, ck = q & 15;
      short8 v = *(const short8*)(Ct + r * 128 + ck * 8);
      *(short8*)(outb16 + (size_t)(row0 + r) * N + col0 + ck * 8) = v;
    }
  } else if (EPI == E8_GELU) {
    u8* Ct = &Bs[0][0];                 // [128][128] u8 = 16 KiB
#pragma unroll
    for (int n = 0; n < 4; ++n) {
      int cl = wc * 64 + n * 16 + lr;
      float bv = bias[col0 + cl];
#pragma unroll
      for (int m = 0; m < 4; ++m) {
#pragma unroll
        for (int i = 0; i < 4; ++i) {
          int rl = wr * 64 + m * 16 + lg * 4 + i;
          float v = acc[m][n][i] * SCL + bv;
          Ct[rl * 128 + cl] = fp8b(gelu_tanh(v) * 16.f);
        }
      }
    }
    __syncthreads();
#pragma unroll
    for (int j = 0; j < 4; ++j) {
      int q = tid + j * 256;
      int r = q >> 3, ck = q & 7;
      *(u32x4*)(outb8 + (size_t)(row0 + r) * N + col0 + ck * 16) =
          *(const u32x4*)(Ct + r * 128 + ck * 16);
    }
  } else if (EPI == E8_RESID) {
#pragma unroll
    for (int n = 0; n < 4; ++n) {
      int cg = col0 + wc * 64 + n * 16 + lr;
      float bv = bias[cg], gv = gate[cg];
#pragma unroll
      for (int m = 0; m < 4; ++m) {
#pragma unroll
        for (int i = 0; i < 4; ++i) {
          int rg = row0 + wr * 64 + m * 16 + lg * 4 + i;
          float v = acc[m][n][i] * SCL + bv;
          float r = res[(size_t)rg * N + cg];
          outf[(size_t)rg * N + cg] = r + gv * v;
        }
      }
    }
  } else {  // E8_ATOMIC: bias+gate pre-applied by init_bias_gate
#pragma unroll
    for (int n = 0; n < 4; ++n) {
      int cg = col0 + wc * 64 + n * 16 + lr;
      float gv = gate[cg];
#pragma unroll
      for (int m = 0; m < 4; ++m) {
#pragma unroll
        for (int i = 0; i < 4; ++i) {
          int rg = row0 + wr * 64 + m * 16 + lg * 4 + i;
          atomicAdd(&outf[(size_t)rg * N + cg], gv * (acc[m][n][i] * SCL));
        }
      }
    }
  }
}

// ---------------- flash attention, swapped-QK^T, register-pipelined K/V ----------------
template <int MASKED, int PRE>
static __device__ __forceinline__ void attn_tile3(short8* kf, const u16* KtNext,
                                                  const u16* Vp0, const u16* Vp1,
                                                  const short8* qf, int kb, int q0, int l31, int hi,
                                                  float& m, float& lsum, f32x16& o0, f32x16& o1) {
  short8 vf0[4], vf1[4];
#pragma unroll
  for (int ks = 0; ks < 4; ++ks) {
    vf0[ks] = *(const short8*)(Vp0 + ks * 16 + hi * 8);
    vf1[ks] = *(const short8*)(Vp1 + ks * 16 + hi * 8);
  }
  f32x16 s0 = {}, s1 = {};
  __builtin_amdgcn_s_setprio(1);
#pragma unroll
  for (int s = 0; s < 4; ++s) {
    s0 = mfma32(kf[s], qf[s], s0);       // S^T[k][q]
    s1 = mfma32(kf[4 + s], qf[s], s1);
  }
  __builtin_amdgcn_s_setprio(0);
  if (PRE) {
    const u16* kp0 = KtNext + (size_t)l31 * 64 + hi * 8;
    const u16* kp1 = KtNext + (size_t)(32 + l31) * 64 + hi * 8;
#pragma unroll
    for (int s = 0; s < 4; ++s) {
      kf[s] = *(const short8*)(kp0 + s * 16);
      kf[4 + s] = *(const short8*)(kp1 + s * 16);
    }
  }
  if (MASKED) {
    int qg = q0 + l31;
#pragma unroll
    for (int r = 0; r < 16; ++r) {
      int kk = kb + (r & 3) + 8 * (r >> 2) + 4 * hi;
      if (kk > qg) s0[r] = -INFINITY;
      if (kk + 32 > qg) s1[r] = -INFINITY;
    }
  }
  float pm = -INFINITY;
#pragma unroll
  for (int r = 0; r < 16; ++r) pm = fmaxf(pm, fmaxf(s0[r], s1[r]));
  pm = fmaxf(pm, __shfl_xor(pm, 32));
  if (!__all(pm <= m + DEFER_THR)) {
    float mn = fmaxf(m, pm);
    float al = exp2f(m - mn);
    m = mn;
    lsum *= al;
#pragma unroll
    for (int r = 0; r < 16; ++r) {
      float alr = __shfl(al, (r & 3) + 8 * (r >> 2) + 4 * hi);
      o0[r] *= alr;
      o1[r] *= alr;
    }
  }
  float ts = 0.f;
#pragma unroll
  for (int r = 0; r < 16; ++r) {
    float p0 = exp2f(s0[r] - m);
    float p1 = exp2f(s1[r] - m);
    s0[r] = p0; s1[r] = p1;
    ts += p0 + p1;
  }
  ts += __shfl_xor(ts, 32);
  lsum += ts;
  auto pack8 = [&](float a0, float a1, float a2, float a3,
                   float a4, float a5, float a6, float a7) -> short8 {
    u32 c0 = cvtpk_bf16(a0, a1), c1 = cvtpk_bf16(a2, a3);
    u32 c2 = cvtpk_bf16(a4, a5), c3 = cvtpk_bf16(a6, a7);
    u32x2 r02 = __builtin_amdgcn_permlane32_swap(c0, c2, false, false);
    u32x2 r13 = __builtin_amdgcn_permlane32_swap(c1, c3, false, false);
    u32x4 w;
    w[0] = r02[0]; w[1] = r13[0]; w[2] = r02[1]; w[3] = r13[1];
    return __builtin_bit_cast(short8, w);
  };
  short8 pa0 = pack8(s0[0], s0[1], s0[2], s0[3], s0[4], s0[5], s0[6], s0[7]);
  short8 pa1 = pack8(s0[8], s0[9], s0[10], s0[11], s0[12], s0[13], s0[14], s0[15]);
  short8 pa2 = pack8(s1[0], s1[1], s1[2], s1[3], s1[4], s1[5], s1[6], s1[7]);
  short8 pa3 = pack8(s1[8], s1[9], s1[10], s1[11], s1[12], s1[13], s1[14], s1[15]);
  short8 pa[4] = {pa0, pa1, pa2, pa3};
  __builtin_amdgcn_s_setprio(1);
#pragma unroll
  for (int ks = 0; ks < 4; ++ks) {
    o0 = mfma32(pa[ks], vf0[ks], o0);
    o1 = mfma32(pa[ks], vf1[ks], o1);
  }
  __builtin_amdgcn_s_setprio(0);
}

template <int CAUSAL>
__global__ __launch_bounds__(256) void flash_attn2(const u16* __restrict__ Q, const u16* __restrict__ K,
                                                   const u16* __restrict__ Vt, u8* __restrict__ O,
                                                   int Lq, int Lk) {
  const int wid = threadIdx.x >> 6, lane = threadIdx.x & 63;
  const int l31 = lane & 31, hi = lane >> 5;
  int wg = blockIdx.x * 4 + wid;
  int bh = wg & 63;
  int qc = wg >> 6;
  if (CAUSAL) qc = (Lq >> 5) - 1 - qc;
  int q0 = qc << 5;

  const u16* Qb = Q + ((size_t)bh * Lq + q0) * 64;
  const u16* Kb = K + (size_t)bh * Lk * 64;
  const u16* Vb = Vt + (size_t)bh * 64 * Lk;

  short8 qf[4];
#pragma unroll
  for (int s = 0; s < 4; ++s) qf[s] = *(const short8*)(Qb + (size_t)l31 * 64 + s * 16 + hi * 8);

  f32x16 o0 = {}, o1 = {};
  float m = -INFINITY, lsum = 0.f;

  const u16* Kt = Kb;
  const u16* Vp0 = Vb + (size_t)l31 * Lk;
  const u16* Vp1 = Vb + (size_t)(32 + l31) * Lk;

  short8 kf[8];
  {
    const u16* kp0 = Kt + (size_t)l31 * 64 + hi * 8;
    const u16* kp1 = Kt + (size_t)(32 + l31) * 64 + hi * 8;
#pragma unroll
    for (int s = 0; s < 4; ++s) {
      kf[s] = *(const short8*)(kp0 + s * 16);
      kf[4 + s] = *(const short8*)(kp1 + s * 16);
    }
  }

  int nt = CAUSAL ? ((q0 >> 6) + 1) : (Lk >> 6);
  for (int t = 0; t < nt - 1; ++t) {
    attn_tile3<0, 1>(kf, Kt + 64 * 64, Vp0, Vp1, qf, t * 64, q0, l31, hi, m, lsum, o0, o1);
    Kt += 64 * 64; Vp0 += 64; Vp1 += 64;
  }
  if (CAUSAL)
    attn_tile3<1, 0>(kf, nullptr, Vp0, Vp1, qf, (nt - 1) * 64, q0, l31, hi, m, lsum, o0, o1);
  else
    attn_tile3<0, 0>(kf, nullptr, Vp0, Vp1, qf, (nt - 1) * 64, q0, l31, hi, m, lsum, o0, o1);

  float myinv = AOSCL / lsum;
  int b = bh >> 4, h = bh & 15;
#pragma unroll
  for (int r = 0; r < 16; ++r) {
    int cr = (r & 3) + 8 * (r >> 2) + 4 * hi;
    float li = __shfl(myinv, cr);
    u8* op = O + ((size_t)b * Lq + q0 + cr) * 1024 + h * 64;
    op[l31] = fp8b(o0[r] * li);
    op[32 + l31] = fp8b(o1[r] * li);
  }
}

// ---------------- launch ----------------
extern "C" void kernel_launch(void* const* d_in, const int* in_sizes, int n_in,
                              void* d_out, int out_size, void* d_ws, size_t ws_size,
                              hipStream_t stream) {
  (void)in_sizes; (void)n_in; (void)out_size;
  if (ws_size < WS_NEED) return;  // need ~105 MB scratch

  const float* x     = (const float*)d_in[0];
  const float* ctx   = (const float*)d_in[1];
  const float* g_msa = (const float*)d_in[3];
  const float* g_ca  = (const float*)d_in[4];
  const float* g_mlp = (const float*)d_in[5];
  const float* n1w = (const float*)d_in[6],  *n1b = (const float*)d_in[7];
  const float* n2w = (const float*)d_in[8],  *n2b = (const float*)d_in[9];
  const float* n3w = (const float*)d_in[10], *n3b = (const float*)d_in[11];
  const float* sa_qw = (const float*)d_in[12], *sa_kw = (const float*)d_in[14];
  const float* sa_vw = (const float*)d_in[16], *sa_pw = (const float*)d_in[18];
  const float* sa_qb = (const float*)d_in[13], *sa_kb = (const float*)d_in[15];
  const float* sa_vb = (const float*)d_in[17], *sa_pb = (const float*)d_in[19];
  const float* ca_qw = (const float*)d_in[20], *ca_qb = (const float*)d_in[21];
  const float* ca_kw = (const float*)d_in[22], *ca_kb = (const float*)d_in[23];
  const float* ca_vw = (const float*)d_in[24], *ca_vb = (const float*)d_in[25];
  const float* ca_pw = (const float*)d_in[26], *ca_pb = (const float*)d_in[27];
  const float* fc1w = (const float*)d_in[28], *fc1b = (const float*)d_in[29];
  const float* fc2w = (const float*)d_in[30], *fc2b = (const float*)d_in[31];

  char* ws = (char*)d_ws;
  float* out = (float*)d_out;
  float* tcos = (float*)(ws + OFF_TCOS);
  float* tsin = (float*)(ws + OFF_TSIN);
  u16* QKV  = (u16*)(ws + OFF_QKV);
  u16* QR   = (u16*)(ws + OFF_QR);
  u16* KR   = (u16*)(ws + OFF_KR);
  u16* VT   = (u16*)(ws + OFF_VT);
  u8*  AO8  = (u8*)(ws + OFF_AO);
  u8*  H8   = (u8*)(ws + OFF_H);
  u8*  U8   = (u8*)(ws + OFF_U);
  u8*  W8QKV  = (u8*)(ws + OFF_W8QKV);
  u8*  W8SAP  = (u8*)(ws + OFF_W8SAP);
  u8*  W8CAQ  = (u8*)(ws + OFF_W8CAQ);
  u8*  W8CAKV = (u8*)(ws + OFF_W8CAKV);
  u8*  W8CAP  = (u8*)(ws + OFF_W8CAP);
  u8*  W8FC1  = (u8*)(ws + OFF_W8FC1);
  u8*  W8FC2  = (u8*)(ws + OFF_W8FC2);
  u8*  CTX8   = (u8*)(ws + OFF_CTX8);

  build_tab<<<dim3(128), dim3(256), 0, stream>>>(tcos, tsin);
  CvtF8 cf;
  cf.s[0] = sa_qw; cf.s[1] = sa_kw; cf.s[2] = sa_vw; cf.s[3] = sa_pw;
  cf.s[4] = ca_qw; cf.s[5] = ca_kw; cf.s[6] = ca_vw; cf.s[7] = ca_pw;
  cf.s[8] = fc1w;  cf.s[9] = fc2w;
  cvt_fp8c<<<dim3(18432), dim3(256), 0, stream>>>(cf, ctx, W8QKV);
  Cp5 cp;
  cp.s[0] = sa_qb; cp.s[1] = sa_kb; cp.s[2] = sa_vb; cp.s[3] = ca_kb; cp.s[4] = ca_vb;
  copy5<<<dim3(20), dim3(256), 0, stream>>>(cp, (float*)(ws + OFF_BSAQKV));

  // ---- self-attention ----
  ln_fp8<<<dim3(NTOK), dim3(256), 0, stream>>>(x, n1w, n1b, H8);
  gemm8<E8_BF16><<<dim3(3072 / 128, NTOK / 128), dim3(256), 0, stream>>>(
      H8, W8QKV, (float*)(ws + OFF_BSAQKV), QKV, nullptr, nullptr, nullptr, nullptr,
      NTOK, 3072, 1024, 1);
  {
    Rope2 r;
    r.j[0] = {QKV, QR, 3072, 0,    LQ, NTOK, QSCALE};
    r.j[1] = {QKV, KR, 3072, 1024, LQ, NTOK, 1.0f};
    rope2<<<dim3(NTOK, 2), dim3(128), 0, stream>>>(r, tcos, tsin);
  }
  vtrans<<<dim3(LQ / 64, Bn * H), dim3(256), 0, stream>>>(QKV, 3072, 2048, VT, LQ);
  flash_attn2<1><<<dim3(512), dim3(256), 0, stream>>>(QR, KR, VT, AO8, LQ, LQ);
  gemm8<E8_RESID><<<dim3(1024 / 128, NTOK / 128), dim3(256), 0, stream>>>(
      AO8, W8SAP, sa_pb, nullptr, nullptr, out, x, g_msa, NTOK, 1024, 1024, 1);

  // ---- cross-attention ----
  ln_fp8<<<dim3(NTOK), dim3(256), 0, stream>>>(out, n2w, n2b, H8);
  gemm8<E8_BF16><<<dim3(1024 / 128, NTOK / 128), dim3(256), 0, stream>>>(
      H8, W8CAQ, ca_qb, (u16*)(ws + OFF_CAQ), nullptr, nullptr, nullptr, nullptr,
      NTOK, 1024, 1024, 1);
  gemm8<E8_BF16><<<dim3(2048 / 128, NCTX / 128), dim3(256), 0, stream>>>(
      CTX8, W8CAKV, (float*)(ws + OFF_BCAKV), (u16*)(ws + OFF_CAKV), nullptr, nullptr,
      nullptr, nullptr, NCTX, 2048, 1024, 1);
  {
    Rope2 r;
    r.j[0] = {(u16*)(ws + OFF_CAQ),  QR, 1024, 0, LQ, NTOK, QSCALE};
    r.j[1] = {(u16*)(ws + OFF_CAKV), KR, 2048, 0, LC, NCTX, 1.0f};
    rope2<<<dim3(NTOK, 2), dim3(128), 0, stream>>>(r, tcos, tsin);
  }
  vtrans<<<dim3(LC / 64, Bn * H), dim3(256), 0, stream>>>(
      (u16*)(ws + OFF_CAKV), 2048, 1024, VT, LC);
  flash_attn2<0><<<dim3(512), dim3(256), 0, stream>>>(QR, KR, VT, AO8, LQ, LC);
  gemm8<E8_RESID><<<dim3(1024 / 128, NTOK / 128), dim3(256), 0, stream>>>(
      AO8, W8CAP, ca_pb, nullptr, nullptr, out, out, g_ca, NTOK, 1024, 1024, 1);

  // ---- MLP (fp8 MX path) ----
  ln_fp8<<<dim3(NTOK), dim3(256), 0, stream>>>(out, n3w, n3b, H8);
  gemm8<E8_GELU><<<dim3(4096 / 128, NTOK / 128), dim3(256), 0, stream>>>(
      H8, W8FC1, fc1b, nullptr, U8, nullptr, nullptr, nullptr, NTOK, 4096, 1024, 1);
  // fc2: split-K x4 atomic (1024 blocks -> 3-4 blocks/CU); bias+gate pre-applied
  init_bias_gate<<<dim3(4096), dim3(256), 0, stream>>>(out, fc2b, g_mlp);
  gemm8<E8_ATOMIC><<<dim3(1024 / 128, NTOK / 128, 4), dim3(256), 0, stream>>>(
      U8, W8FC2, nullptr, nullptr, nullptr, out, nullptr, g_mlp, NTOK, 1024, 4096, 4);
}

// Round 18
// 325.460 us; speedup vs baseline: 1.1724x; 1.1724x over previous
//
#include <hip/hip_runtime.h>
#include <math.h>

#if !__has_builtin(__builtin_amdgcn_cvt_pk_fp8_f32)
#include <hip/hip_fp8.h>
#endif

typedef __attribute__((ext_vector_type(8))) short short8;
typedef __attribute__((ext_vector_type(4))) float f32x4;
typedef __attribute__((ext_vector_type(16))) float f32x16;
typedef unsigned char u8;
typedef unsigned short u16;
typedef unsigned int u32;
typedef __attribute__((ext_vector_type(2))) u32 u32x2;
typedef __attribute__((ext_vector_type(4))) u32 u32x4;
typedef __attribute__((ext_vector_type(8))) int i32x8;
typedef unsigned long long u64;

static constexpr int E = 1024, H = 16, LQ = 1024, LC = 512, Bn = 4, FF = 4096;
static constexpr int NTOK = Bn * LQ;   // 4096
static constexpr int NCTX = Bn * LC;   // 2048

#define QSCALE 0.1803368801111244f
#define DEFER_THR 11.5f
#define AOSCL 16.0f

// ---------------- workspace layout (bytes) ----------------
static constexpr size_t OFF_TCOS   = 0;
static constexpr size_t OFF_TSIN   = OFF_TCOS + (size_t)LQ*32*4;
static constexpr size_t OFF_BSAQKV = OFF_TSIN + (size_t)LQ*32*4;
static constexpr size_t OFF_BCAKV  = OFF_BSAQKV + 16384;
static constexpr size_t OFF_W8     = OFF_BCAKV + 16384;
static constexpr size_t OFF_W8QKV  = OFF_W8;                               // [3072][1024]
static constexpr size_t OFF_W8SAP  = OFF_W8QKV  + (size_t)3*1048576;
static constexpr size_t OFF_W8CAQ  = OFF_W8SAP  + (size_t)1*1048576;
static constexpr size_t OFF_W8CAKV = OFF_W8CAQ  + (size_t)1*1048576;
static constexpr size_t OFF_W8CAP  = OFF_W8CAKV + (size_t)2*1048576;
static constexpr size_t OFF_W8FC1  = OFF_W8CAP  + (size_t)1*1048576;
static constexpr size_t OFF_W8FC2  = OFF_W8FC1  + (size_t)4*1048576;
static constexpr size_t OFF_CTX8   = OFF_W8FC2  + (size_t)4*1048576;
static constexpr size_t OFF_CTXB   = OFF_W8 + (size_t)30*1048576 + (size_t)2048*1024*2;
static constexpr size_t OFF_H      = OFF_CTXB   + (size_t)2048*1024*2;
static constexpr size_t OFF_QKV    = OFF_H      + (size_t)4096*1024*2;
static constexpr size_t OFF_CAQ    = OFF_QKV;
static constexpr size_t OFF_CAKV   = OFF_QKV + (size_t)4096*1024*2;
static constexpr size_t OFF_QR     = OFF_QKV + (size_t)4096*3072*2;
static constexpr size_t OFF_KR     = OFF_QR  + (size_t)4096*1024*2;
static constexpr size_t OFF_VT     = OFF_KR  + (size_t)4096*1024*2;
static constexpr size_t OFF_AO     = OFF_VT  + (size_t)4096*1024*2;
static constexpr size_t OFF_U      = OFF_QKV;
static constexpr size_t WS_NEED    = OFF_AO + (size_t)4096*1024*2;

// ---------------- helpers ----------------
static __device__ __forceinline__ float bf2f(u16 u) {
  union { u32 i; float f; } un; un.i = ((u32)u) << 16; return un.f;
}
static __device__ __forceinline__ u16 f2bf(float f) {  // RNE
  union { float f; u32 u; } un; un.f = f;
  u32 u = un.u;
  return (u16)((u + 0x7FFFu + ((u >> 16) & 1u)) >> 16);
}
static __device__ __forceinline__ u64 pack4(u16 a, u16 b, u16 c, u16 d) {
  return (u64)a | ((u64)b << 16) | ((u64)c << 32) | ((u64)d << 48);
}
static __device__ __forceinline__ f32x16 mfma32(short8 a, short8 b, f32x16 c) {
  return __builtin_amdgcn_mfma_f32_32x32x16_bf16(a, b, c, 0, 0, 0);
}
static __device__ __forceinline__ void gload_lds16(void* lds, const void* g) {
  __builtin_amdgcn_global_load_lds(
      (const __attribute__((address_space(1))) void*)g,
      (__attribute__((address_space(3))) void*)lds, 16, 0, 0);
}
static __device__ __forceinline__ float gelu_tanh(float x) {
  float z2 = 1.5957691216057308f * (x + 0.044715f * x * x * x);
  float e = __expf(z2);
  float r = __builtin_amdgcn_rcpf(e + 1.0f);
  return x - x * r;
}
static __device__ __forceinline__ u32 cvtpk_bf16(float lo, float hi) {
  u32 r;
  asm("v_cvt_pk_bf16_f32 %0, %1, %2" : "=v"(r) : "v"(lo), "v"(hi));
  return r;
}
static __device__ __forceinline__ u32 pack_fp8x4(float a, float b, float c, float d) {
#if __has_builtin(__builtin_amdgcn_cvt_pk_fp8_f32)
  u32 r = (u32)__builtin_amdgcn_cvt_pk_fp8_f32(a, b, 0, false);
  r = (u32)__builtin_amdgcn_cvt_pk_fp8_f32(c, d, (int)r, true);
  return r;
#else
  __hip_fp8_e4m3 qa(a), qb(b), qc(c), qd(d);
  return (u32)qa.__x | ((u32)qb.__x << 8) | ((u32)qc.__x << 16) | ((u32)qd.__x << 24);
#endif
}
static __device__ __forceinline__ u8 fp8b(float f) {
#if __has_builtin(__builtin_amdgcn_cvt_pk_fp8_f32)
  return (u8)((u32)__builtin_amdgcn_cvt_pk_fp8_f32(f, f, 0, false) & 0xFFu);
#else
  __hip_fp8_e4m3 t(f); return t.__x;
#endif
}

// ---------------- small kernels ----------------
__global__ __launch_bounds__(256) void build_tab(float* __restrict__ ct, float* __restrict__ st) {
  int idx = blockIdx.x * 256 + threadIdx.x;
  int pos = idx >> 5, i = idx & 31;
  float inv = powf(10000.f, -(float)i * (1.f / 32.f));
  float a = (float)pos * inv;
  ct[idx] = cosf(a);
  st[idx] = sinf(a);
}

struct CvtF8 { const float* s[10]; };
__global__ __launch_bounds__(256) void cvt_fp8c(CvtF8 a, const float* __restrict__ ctx,
                                                u8* __restrict__ dst) {
  u32 gid = blockIdx.x * 256 + threadIdx.x;
  u32 seg = gid >> 18, off = gid & 262143u;
  const float* s;
  float scl = 256.f;
  if (seg < 8)       s = a.s[seg];
  else if (seg < 12) s = a.s[8] + (size_t)(seg - 8) * 1048576;
  else if (seg < 16) s = a.s[9] + (size_t)(seg - 12) * 1048576;
  else             { s = ctx + (size_t)(seg - 16) * 1048576; scl = 16.f; }
  float4 v = *(const float4*)(s + (size_t)off * 4);
  *(u32*)(dst + (size_t)seg * 1048576 + (size_t)off * 4) =
      pack_fp8x4(v.x * scl, v.y * scl, v.z * scl, v.w * scl);
}

struct Cp5 { const float* s[5]; };
__global__ __launch_bounds__(256) void copy5(Cp5 a, float* __restrict__ dst) {
  int gid = blockIdx.x * 256 + threadIdx.x;
  int s = gid >> 10, off = gid & 1023;
  int doff = (s < 3) ? s * 1024 : 4096 + (s - 3) * 1024;
  dst[doff + off] = a.s[s][off];
}

__global__ __launch_bounds__(256) void init_bias_gate(float* __restrict__ out, const float* __restrict__ bias,
                                                      const float* __restrict__ gate) {
  int i = (blockIdx.x * 256 + threadIdx.x) * 4;
  int c = i & 1023;
  float4 o = *(float4*)(out + i);
  o.x += gate[c] * bias[c];
  o.y += gate[c + 1] * bias[c + 1];
  o.z += gate[c + 2] * bias[c + 2];
  o.w += gate[c + 3] * bias[c + 3];
  *(float4*)(out + i) = o;
}

__global__ __launch_bounds__(256) void ln_fp8(const float* __restrict__ x, const float* __restrict__ w,
                                              const float* __restrict__ b, u8* __restrict__ out) {
  __shared__ float red[4];
  int row = blockIdx.x, tid = threadIdx.x;
  const float* xr = x + (size_t)row * 1024;
  float4 v = ((const float4*)xr)[tid];
  float s = v.x + v.y + v.z + v.w;
#pragma unroll
  for (int off = 32; off; off >>= 1) s += __shfl_xor(s, off);
  if ((tid & 63) == 0) red[tid >> 6] = s;
  __syncthreads();
  float mean = (red[0] + red[1] + red[2] + red[3]) * (1.f / 1024.f);
  float dx = v.x - mean, dy = v.y - mean, dz = v.z - mean, dw = v.w - mean;
  float sq = dx * dx + dy * dy + dz * dz + dw * dw;
#pragma unroll
  for (int off = 32; off; off >>= 1) sq += __shfl_xor(sq, off);
  __syncthreads();
  if ((tid & 63) == 0) red[tid >> 6] = sq;
  __syncthreads();
  float var = (red[0] + red[1] + red[2] + red[3]) * (1.f / 1024.f);
  float rstd = rsqrtf(var + 1e-6f);
  float4 wv = ((const float4*)w)[tid];
  float4 bv = ((const float4*)b)[tid];
  u32 pk = pack_fp8x4((dx * rstd * wv.x + bv.x) * 16.f, (dy * rstd * wv.y + bv.y) * 16.f,
                      (dz * rstd * wv.z + bv.z) * 16.f, (dw * rstd * wv.w + bv.w) * 16.f);
  *(u32*)(out + (size_t)row * 1024 + tid * 4) = pk;
}

struct RopeJob { const u16* src; u16* dst; int ld, col0, Lper, T; float scale; };
struct Rope2 { RopeJob j[2]; };
__global__ __launch_bounds__(128) void rope2(Rope2 a, const float* __restrict__ cosT,
                                             const float* __restrict__ sinT) {
  RopeJob jb = a.j[blockIdx.y];
  int t = blockIdx.x;
  if (t >= jb.T) return;
  int b = t / jb.Lper, l = t - b * jb.Lper;
  int tid = threadIdx.x;
  int e0 = tid * 8;
  int h = e0 >> 6, d0 = e0 & 63;
  short8 vv = *(const short8*)(jb.src + (size_t)t * jb.ld + jb.col0 + e0);
  short8 ov;
#pragma unroll
  for (int j = 0; j < 4; ++j) {
    float x1 = bf2f((u16)vv[2 * j]);
    float x2 = bf2f((u16)vv[2 * j + 1]);
    int i = (d0 >> 1) + j;
    float c = cosT[l * 32 + i], s = sinT[l * 32 + i];
    ov[2 * j]     = (short)f2bf((x1 * c - x2 * s) * jb.scale);
    ov[2 * j + 1] = (short)f2bf((x1 * s + x2 * c) * jb.scale);
  }
  *(short8*)(jb.dst + (((size_t)b * H + h) * jb.Lper + l) * 64 + d0) = ov;
}

__global__ __launch_bounds__(256) void vtrans(const u16* __restrict__ src, int ld, int col0,
                                              u16* __restrict__ dst, int Lper) {
  __shared__ u16 tile[64][72];
  int bh = blockIdx.y;
  int b = bh >> 4, h = bh & 15;
  int l0 = blockIdx.x * 64;
  int tid = threadIdx.x;
#pragma unroll
  for (int j = 0; j < 2; ++j) {
    int c = tid + j * 256;
    int i = c >> 3, d0 = (c & 7) * 8;
    short8 v = *(const short8*)(src + (size_t)(b * Lper + l0 + i) * ld + col0 + h * 64 + d0);
    *(short8*)(&tile[i][d0]) = v;
  }
  __syncthreads();
#pragma unroll
  for (int j = 0; j < 2; ++j) {
    int c = tid + j * 256;
    int d = c >> 3, lc = (c & 7) * 8;
    short8 v;
#pragma unroll
    for (int k = 0; k < 8; ++k) v[k] = (short)tile[lc + k][d];
    *(short8*)(dst + (((size_t)bh) * 64 + d) * Lper + l0 + lc) = v;
  }
}

// ---------------- fp8 MX GEMM (R16-proven): A+B LDS-staged, 2 blocks/CU ----------------
enum { E8_BF16 = 0, E8_GELU = 1, E8_ATOMIC = 2, E8_RESID = 3 };

template <int EPI>
__global__ __launch_bounds__(256, 2) void gemm8(const u8* __restrict__ A, const u8* __restrict__ W,
                                                const float* __restrict__ bias, u16* outb16,
                                                u8* outb8, float* outf, const float* res,
                                                const float* __restrict__ gate,
                                                int M, int N, int K, int kchunks) {
  __shared__ u8 As[2][128 * 128];
  __shared__ u8 Bs[2][128 * 128];

  int nwg = gridDim.x * gridDim.y;
  int bid = blockIdx.y * gridDim.x + blockIdx.x;
  int cpx = nwg >> 3;
  int swz = (bid & 7) * cpx + (bid >> 3);
  int bx = swz % gridDim.x, by = swz / gridDim.x;
  int row0 = by * 128, col0 = bx * 128;

  const int Kc = K / kchunks;
  const int kbase = blockIdx.z * Kc;

  int tid = threadIdx.x;
  int lane = tid & 63, wid = tid >> 6;
  int wr = wid >> 1, wc = wid & 1;
  int lr = lane & 15, lg = lane >> 4;

  u32 aoff[4], boff[4];
  int ldso[4];
#pragma unroll
  for (int j = 0; j < 4; ++j) {
    int q = tid + j * 256;
    int r = q >> 3, p = q & 7, sp = p ^ (r & 7);
    aoff[j] = (u32)(row0 + r) * (u32)K + sp * 16;
    boff[j] = (u32)(col0 + r) * (u32)K + sp * 16;
    ldso[j] = q * 16;
  }

  f32x4 acc[4][4] = {};
  const int nkt = Kc >> 7;

  auto rdfrag = [&](const u8* base, int r, i32x8& f) {
    const u8* rp = base + r * 128;
    int ck = lg * 2;
    u32x4 lo = *(const u32x4*)(rp + ((ck) ^ (r & 7)) * 16);
    u32x4 hh = *(const u32x4*)(rp + ((ck + 1) ^ (r & 7)) * 16);
    i32x8 v;
    v[0] = (int)lo[0]; v[1] = (int)lo[1]; v[2] = (int)lo[2]; v[3] = (int)lo[3];
    v[4] = (int)hh[0]; v[5] = (int)hh[1]; v[6] = (int)hh[2]; v[7] = (int)hh[3];
    f = v;
  };

#pragma unroll
  for (int j = 0; j < 4; ++j) {
    gload_lds16(&As[0][ldso[j]], A + aoff[j] + kbase);
    gload_lds16(&Bs[0][ldso[j]], W + boff[j] + kbase);
  }
  __syncthreads();

  for (int kt = 0; kt < nkt; ++kt) {
    int cur = kt & 1;
    if (kt + 1 < nkt) {
      int k0 = kbase + ((kt + 1) << 7);
#pragma unroll
      for (int j = 0; j < 4; ++j) {
        gload_lds16(&As[cur ^ 1][ldso[j]], A + aoff[j] + k0);
        gload_lds16(&Bs[cur ^ 1][ldso[j]], W + boff[j] + k0);
      }
    }
    i32x8 a[4], b[4];
#pragma unroll
    for (int m = 0; m < 4; ++m) rdfrag(&As[cur][0], wr * 64 + m * 16 + lr, a[m]);
#pragma unroll
    for (int n = 0; n < 4; ++n) rdfrag(&Bs[cur][0], wc * 64 + n * 16 + lr, b[n]);
    __builtin_amdgcn_s_setprio(1);
#pragma unroll
    for (int m = 0; m < 4; ++m)
#pragma unroll
      for (int n = 0; n < 4; ++n)
        acc[m][n] = __builtin_amdgcn_mfma_scale_f32_16x16x128_f8f6f4(
            a[m], b[n], acc[m][n], 0, 0, 0, 0x7F7F7F7F, 0, 0x7F7F7F7F);
    __builtin_amdgcn_s_setprio(0);
    __syncthreads();
  }

  constexpr float SCL = 1.f / 4096.f;
  if (EPI == E8_BF16) {
    u16* Ct = (u16*)&As[0][0];
#pragma unroll
    for (int n = 0; n < 4; ++n) {
      int cl = wc * 64 + n * 16 + lr;
      float bv = bias[col0 + cl];
#pragma unroll
      for (int m = 0; m < 4; ++m) {
#pragma unroll
        for (int i = 0; i < 4; ++i) {
          int rl = wr * 64 + m * 16 + lg * 4 + i;
          Ct[rl * 128 + cl] = f2bf(acc[m][n][i] * SCL + bv);
        }
      }
    }
    __syncthreads();
#pragma unroll
    for (int j = 0; j < 8; ++j) {
      u32 q = (u32)tid + j * 256;
      u32 r = q >> 4, ck = q & 15;
      short8 v = *(const short8*)(Ct + r * 128 + ck * 8);
      *(short8*)(outb16 + (size_t)(row0 + r) * N + col0 + ck * 8) = v;
    }
  } else if (EPI == E8_GELU) {
    u8* Ct = &As[0][0];
#pragma unroll
    for (int n = 0; n < 4; ++n) {
      int cl = wc * 64 + n * 16 + lr;
      float bv = bias[col0 + cl];
#pragma unroll
      for (int m = 0; m < 4; ++m) {
#pragma unroll
        for (int i = 0; i < 4; ++i) {
          int rl = wr * 64 + m * 16 + lg * 4 + i;
          float v = acc[m][n][i] * SCL + bv;
          Ct[rl * 128 + cl] = fp8b(gelu_tanh(v) * 16.f);
        }
      }
    }
    __syncthreads();
#pragma unroll
    for (int j = 0; j < 4; ++j) {
      int q = tid + j * 256;
      int r = q >> 3, ck = q & 7;
      *(u32x4*)(outb8 + (size_t)(row0 + r) * N + col0 + ck * 16) =
          *(const u32x4*)(Ct + r * 128 + ck * 16);
    }
  } else if (EPI == E8_RESID) {
#pragma unroll
    for (int n = 0; n < 4; ++n) {
      int cg = col0 + wc * 64 + n * 16 + lr;
      float bv = bias[cg], gv = gate[cg];
#pragma unroll
      for (int m = 0; m < 4; ++m) {
#pragma unroll
        for (int i = 0; i < 4; ++i) {
          int rg = row0 + wr * 64 + m * 16 + lg * 4 + i;
          float v = acc[m][n][i] * SCL + bv;
          float r = res[(size_t)rg * N + cg];
          outf[(size_t)rg * N + cg] = r + gv * v;
        }
      }
    }
  } else {
#pragma unroll
    for (int n = 0; n < 4; ++n) {
      int cg = col0 + wc * 64 + n * 16 + lr;
      float gv = gate[cg];
#pragma unroll
      for (int m = 0; m < 4; ++m) {
#pragma unroll
        for (int i = 0; i < 4; ++i) {
          int rg = row0 + wr * 64 + m * 16 + lg * 4 + i;
          atomicAdd(&outf[(size_t)rg * N + cg], gv * (acc[m][n][i] * SCL));
        }
      }
    }
  }
}

// ---------------- gemm8p: B LDS-staged + A register-prefetched one K-tile ahead ----
// R11-proven pattern: A(t+1) loads issue BEFORE tile t's MFMA cluster -> ~full
// iteration of latency cover. Halves the per-iter drain (16 KB). fc2 only.
template <int EPI>
__global__ __launch_bounds__(256, 2) void gemm8p(const u8* __restrict__ A, const u8* __restrict__ W,
                                                 const float* __restrict__ bias, float* outf,
                                                 const float* __restrict__ gate,
                                                 int M, int N, int K, int kchunks) {
  __shared__ u8 Bs[2][128 * 128];   // 32 KiB

  int nwg = gridDim.x * gridDim.y;
  int bid = blockIdx.y * gridDim.x + blockIdx.x;
  int cpx = nwg >> 3;
  int swz = (bid & 7) * cpx + (bid >> 3);
  int bx = swz % gridDim.x, by = swz / gridDim.x;
  int row0 = by * 128, col0 = bx * 128;

  const int Kc = K / kchunks;
  const int kbase = blockIdx.z * Kc;

  int tid = threadIdx.x;
  int lane = tid & 63, wid = tid >> 6;
  int wr = wid >> 1, wc = wid & 1;
  int lr = lane & 15, lg = lane >> 4;

  u32 boff[4];
  int ldso[4];
#pragma unroll
  for (int j = 0; j < 4; ++j) {
    int q = tid + j * 256;
    int r = q >> 3, p = q & 7, sp = p ^ (r & 7);
    boff[j] = (u32)(col0 + r) * (u32)K + sp * 16;
    ldso[j] = q * 16;
  }
  const u8* arow[4];
#pragma unroll
  for (int m = 0; m < 4; ++m)
    arow[m] = A + (size_t)(row0 + wr * 64 + m * 16 + lr) * K + lg * 32 + kbase;

  f32x4 acc[4][4] = {};
  const int nkt = Kc >> 7;             // even for all call sites (fc2 x2: 16)

  auto rdA4 = [&](int kb, i32x8* f) {
#pragma unroll
    for (int m = 0; m < 4; ++m) {
      const u8* rp = arow[m] + kb;
      u32x4 lo = *(const u32x4*)(rp);
      u32x4 hh = *(const u32x4*)(rp + 16);
      i32x8 v;
      v[0] = (int)lo[0]; v[1] = (int)lo[1]; v[2] = (int)lo[2]; v[3] = (int)lo[3];
      v[4] = (int)hh[0]; v[5] = (int)hh[1]; v[6] = (int)hh[2]; v[7] = (int)hh[3];
      f[m] = v;
    }
  };
  auto rdB = [&](const u8* base, int r, i32x8& f) {
    const u8* rp = base + r * 128;
    int ck = lg * 2;
    u32x4 lo = *(const u32x4*)(rp + ((ck) ^ (r & 7)) * 16);
    u32x4 hh = *(const u32x4*)(rp + ((ck + 1) ^ (r & 7)) * 16);
    i32x8 v;
    v[0] = (int)lo[0]; v[1] = (int)lo[1]; v[2] = (int)lo[2]; v[3] = (int)lo[3];
    v[4] = (int)hh[0]; v[5] = (int)hh[1]; v[6] = (int)hh[2]; v[7] = (int)hh[3];
    f = v;
  };
  auto stageB = [&](int buf, int k0) {
#pragma unroll
    for (int j = 0; j < 4; ++j) gload_lds16(&Bs[buf][ldso[j]], W + boff[j] + k0);
  };

  i32x8 aA[4], aB[4];
  // prologue: stage B(0), load A(0) into regs
  stageB(0, kbase);
  rdA4(0, aA);
  __syncthreads();

  auto step = [&](int kt, i32x8* aCur, i32x8* aNxt) {
    int cur = kt & 1;
    if (kt + 1 < nkt) stageB(cur ^ 1, kbase + ((kt + 1) << 7));
    i32x8 b[4];
#pragma unroll
    for (int n = 0; n < 4; ++n) rdB(&Bs[cur][0], wc * 64 + n * 16 + lr, b[n]);
    if (kt + 1 < nkt) rdA4((kt + 1) << 7, aNxt);   // issue BEFORE the MFMA cluster
    __builtin_amdgcn_s_setprio(1);
#pragma unroll
    for (int m = 0; m < 4; ++m)
#pragma unroll
      for (int n = 0; n < 4; ++n)
        acc[m][n] = __builtin_amdgcn_mfma_scale_f32_16x16x128_f8f6f4(
            aCur[m], b[n], acc[m][n], 0, 0, 0, 0x7F7F7F7F, 0, 0x7F7F7F7F);
    __builtin_amdgcn_s_setprio(0);
    __syncthreads();
  };

  for (int kt = 0; kt < nkt; kt += 2) {   // nkt even: static reg double-buffer
    step(kt, aA, aB);
    step(kt + 1, aB, aA);
  }

  // E8_ATOMIC epilogue (bias+gate pre-applied by init_bias_gate)
  constexpr float SCL = 1.f / 4096.f;
#pragma unroll
  for (int n = 0; n < 4; ++n) {
    int cg = col0 + wc * 64 + n * 16 + lr;
    float gv = gate[cg];
#pragma unroll
    for (int m = 0; m < 4; ++m) {
#pragma unroll
      for (int i = 0; i < 4; ++i) {
        int rg = row0 + wr * 64 + m * 16 + lg * 4 + i;
        atomicAdd(&outf[(size_t)rg * N + cg], gv * (acc[m][n][i] * SCL));
      }
    }
  }
}

// ---------------- flash attention, swapped-QK^T, register-pipelined K/V ----------------
template <int MASKED, int PRE>
static __device__ __forceinline__ void attn_tile3(short8* kf, const u16* KtNext,
                                                  const u16* Vp0, const u16* Vp1,
                                                  const short8* qf, int kb, int q0, int l31, int hi,
                                                  float& m, float& lsum, f32x16& o0, f32x16& o1) {
  short8 vf0[4], vf1[4];
#pragma unroll
  for (int ks = 0; ks < 4; ++ks) {
    vf0[ks] = *(const short8*)(Vp0 + ks * 16 + hi * 8);
    vf1[ks] = *(const short8*)(Vp1 + ks * 16 + hi * 8);
  }
  f32x16 s0 = {}, s1 = {};
  __builtin_amdgcn_s_setprio(1);
#pragma unroll
  for (int s = 0; s < 4; ++s) {
    s0 = mfma32(kf[s], qf[s], s0);
    s1 = mfma32(kf[4 + s], qf[s], s1);
  }
  __builtin_amdgcn_s_setprio(0);
  if (PRE) {
    const u16* kp0 = KtNext + (size_t)l31 * 64 + hi * 8;
    const u16* kp1 = KtNext + (size_t)(32 + l31) * 64 + hi * 8;
#pragma unroll
    for (int s = 0; s < 4; ++s) {
      kf[s] = *(const short8*)(kp0 + s * 16);
      kf[4 + s] = *(const short8*)(kp1 + s * 16);
    }
  }
  if (MASKED) {
    int qg = q0 + l31;
#pragma unroll
    for (int r = 0; r < 16; ++r) {
      int kk = kb + (r & 3) + 8 * (r >> 2) + 4 * hi;
      if (kk > qg) s0[r] = -INFINITY;
      if (kk + 32 > qg) s1[r] = -INFINITY;
    }
  }
  float pm = -INFINITY;
#pragma unroll
  for (int r = 0; r < 16; ++r) pm = fmaxf(pm, fmaxf(s0[r], s1[r]));
  pm = fmaxf(pm, __shfl_xor(pm, 32));
  if (!__all(pm <= m + DEFER_THR)) {
    float mn = fmaxf(m, pm);
    float al = exp2f(m - mn);
    m = mn;
    lsum *= al;
#pragma unroll
    for (int r = 0; r < 16; ++r) {
      float alr = __shfl(al, (r & 3) + 8 * (r >> 2) + 4 * hi);
      o0[r] *= alr;
      o1[r] *= alr;
    }
  }
  float ts = 0.f;
#pragma unroll
  for (int r = 0; r < 16; ++r) {
    float p0 = exp2f(s0[r] - m);
    float p1 = exp2f(s1[r] - m);
    s0[r] = p0; s1[r] = p1;
    ts += p0 + p1;
  }
  ts += __shfl_xor(ts, 32);
  lsum += ts;
  auto pack8 = [&](float a0, float a1, float a2, float a3,
                   float a4, float a5, float a6, float a7) -> short8 {
    u32 c0 = cvtpk_bf16(a0, a1), c1 = cvtpk_bf16(a2, a3);
    u32 c2 = cvtpk_bf16(a4, a5), c3 = cvtpk_bf16(a6, a7);
    u32x2 r02 = __builtin_amdgcn_permlane32_swap(c0, c2, false, false);
    u32x2 r13 = __builtin_amdgcn_permlane32_swap(c1, c3, false, false);
    u32x4 w;
    w[0] = r02[0]; w[1] = r13[0]; w[2] = r02[1]; w[3] = r13[1];
    return __builtin_bit_cast(short8, w);
  };
  short8 pa0 = pack8(s0[0], s0[1], s0[2], s0[3], s0[4], s0[5], s0[6], s0[7]);
  short8 pa1 = pack8(s0[8], s0[9], s0[10], s0[11], s0[12], s0[13], s0[14], s0[15]);
  short8 pa2 = pack8(s1[0], s1[1], s1[2], s1[3], s1[4], s1[5], s1[6], s1[7]);
  short8 pa3 = pack8(s1[8], s1[9], s1[10], s1[11], s1[12], s1[13], s1[14], s1[15]);
  short8 pa[4] = {pa0, pa1, pa2, pa3};
  __builtin_amdgcn_s_setprio(1);
#pragma unroll
  for (int ks = 0; ks < 4; ++ks) {
    o0 = mfma32(pa[ks], vf0[ks], o0);
    o1 = mfma32(pa[ks], vf1[ks], o1);
  }
  __builtin_amdgcn_s_setprio(0);
}

template <int CAUSAL>
__global__ __launch_bounds__(256) void flash_attn2(const u16* __restrict__ Q, const u16* __restrict__ K,
                                                   const u16* __restrict__ Vt, u8* __restrict__ O,
                                                   int Lq, int Lk) {
  const int wid = threadIdx.x >> 6, lane = threadIdx.x & 63;
  const int l31 = lane & 31, hi = lane >> 5;
  int wg = blockIdx.x * 4 + wid;
  int bh = wg & 63;
  int qc = wg >> 6;
  if (CAUSAL) qc = (Lq >> 5) - 1 - qc;
  int q0 = qc << 5;

  const u16* Qb = Q + ((size_t)bh * Lq + q0) * 64;
  const u16* Kb = K + (size_t)bh * Lk * 64;
  const u16* Vb = Vt + (size_t)bh * 64 * Lk;

  short8 qf[4];
#pragma unroll
  for (int s = 0; s < 4; ++s) qf[s] = *(const short8*)(Qb + (size_t)l31 * 64 + s * 16 + hi * 8);

  f32x16 o0 = {}, o1 = {};
  float m = -INFINITY, lsum = 0.f;

  const u16* Kt = Kb;
  const u16* Vp0 = Vb + (size_t)l31 * Lk;
  const u16* Vp1 = Vb + (size_t)(32 + l31) * Lk;

  short8 kf[8];
  {
    const u16* kp0 = Kt + (size_t)l31 * 64 + hi * 8;
    const u16* kp1 = Kt + (size_t)(32 + l31) * 64 + hi * 8;
#pragma unroll
    for (int s = 0; s < 4; ++s) {
      kf[s] = *(const short8*)(kp0 + s * 16);
      kf[4 + s] = *(const short8*)(kp1 + s * 16);
    }
  }

  int nt = CAUSAL ? ((q0 >> 6) + 1) : (Lk >> 6);
  for (int t = 0; t < nt - 1; ++t) {
    attn_tile3<0, 1>(kf, Kt + 64 * 64, Vp0, Vp1, qf, t * 64, q0, l31, hi, m, lsum, o0, o1);
    Kt += 64 * 64; Vp0 += 64; Vp1 += 64;
  }
  if (CAUSAL)
    attn_tile3<1, 0>(kf, nullptr, Vp0, Vp1, qf, (nt - 1) * 64, q0, l31, hi, m, lsum, o0, o1);
  else
    attn_tile3<0, 0>(kf, nullptr, Vp0, Vp1, qf, (nt - 1) * 64, q0, l31, hi, m, lsum, o0, o1);

  float myinv = AOSCL / lsum;
  int b = bh >> 4, h = bh & 15;
#pragma unroll
  for (int r = 0; r < 16; ++r) {
    int cr = (r & 3) + 8 * (r >> 2) + 4 * hi;
    float li = __shfl(myinv, cr);
    u8* op = O + ((size_t)b * Lq + q0 + cr) * 1024 + h * 64;
    op[l31] = fp8b(o0[r] * li);
    op[32 + l31] = fp8b(o1[r] * li);
  }
}

// ---------------- launch ----------------
extern "C" void kernel_launch(void* const* d_in, const int* in_sizes, int n_in,
                              void* d_out, int out_size, void* d_ws, size_t ws_size,
                              hipStream_t stream) {
  (void)in_sizes; (void)n_in; (void)out_size;
  if (ws_size < WS_NEED) return;

  const float* x     = (const float*)d_in[0];
  const float* ctx   = (const float*)d_in[1];
  const float* g_msa = (const float*)d_in[3];
  const float* g_ca  = (const float*)d_in[4];
  const float* g_mlp = (const float*)d_in[5];
  const float* n1w = (const float*)d_in[6],  *n1b = (const float*)d_in[7];
  const float* n2w = (const float*)d_in[8],  *n2b = (const float*)d_in[9];
  const float* n3w = (const float*)d_in[10], *n3b = (const float*)d_in[11];
  const float* sa_qw = (const float*)d_in[12], *sa_kw = (const float*)d_in[14];
  const float* sa_vw = (const float*)d_in[16], *sa_pw = (const float*)d_in[18];
  const float* sa_qb = (const float*)d_in[13], *sa_kb = (const float*)d_in[15];
  const float* sa_vb = (const float*)d_in[17], *sa_pb = (const float*)d_in[19];
  const float* ca_qw = (const float*)d_in[20], *ca_qb = (const float*)d_in[21];
  const float* ca_kw = (const float*)d_in[22], *ca_kb = (const float*)d_in[23];
  const float* ca_vw = (const float*)d_in[24], *ca_vb = (const float*)d_in[25];
  const float* ca_pw = (const float*)d_in[26], *ca_pb = (const float*)d_in[27];
  const float* fc1w = (const float*)d_in[28], *fc1b = (const float*)d_in[29];
  const float* fc2w = (const float*)d_in[30], *fc2b = (const float*)d_in[31];

  char* ws = (char*)d_ws;
  float* out = (float*)d_out;
  float* tcos = (float*)(ws + OFF_TCOS);
  float* tsin = (float*)(ws + OFF_TSIN);
  u16* QKV  = (u16*)(ws + OFF_QKV);
  u16* QR   = (u16*)(ws + OFF_QR);
  u16* KR   = (u16*)(ws + OFF_KR);
  u16* VT   = (u16*)(ws + OFF_VT);
  u8*  AO8  = (u8*)(ws + OFF_AO);
  u8*  H8   = (u8*)(ws + OFF_H);
  u8*  U8   = (u8*)(ws + OFF_U);
  u8*  W8QKV  = (u8*)(ws + OFF_W8QKV);
  u8*  W8SAP  = (u8*)(ws + OFF_W8SAP);
  u8*  W8CAQ  = (u8*)(ws + OFF_W8CAQ);
  u8*  W8CAKV = (u8*)(ws + OFF_W8CAKV);
  u8*  W8CAP  = (u8*)(ws + OFF_W8CAP);
  u8*  W8FC1  = (u8*)(ws + OFF_W8FC1);
  u8*  W8FC2  = (u8*)(ws + OFF_W8FC2);
  u8*  CTX8   = (u8*)(ws + OFF_CTX8);

  build_tab<<<dim3(128), dim3(256), 0, stream>>>(tcos, tsin);
  CvtF8 cf;
  cf.s[0] = sa_qw; cf.s[1] = sa_kw; cf.s[2] = sa_vw; cf.s[3] = sa_pw;
  cf.s[4] = ca_qw; cf.s[5] = ca_kw; cf.s[6] = ca_vw; cf.s[7] = ca_pw;
  cf.s[8] = fc1w;  cf.s[9] = fc2w;
  cvt_fp8c<<<dim3(18432), dim3(256), 0, stream>>>(cf, ctx, W8QKV);
  Cp5 cp;
  cp.s[0] = sa_qb; cp.s[1] = sa_kb; cp.s[2] = sa_vb; cp.s[3] = ca_kb; cp.s[4] = ca_vb;
  copy5<<<dim3(20), dim3(256), 0, stream>>>(cp, (float*)(ws + OFF_BSAQKV));

  // ---- self-attention ----
  ln_fp8<<<dim3(NTOK), dim3(256), 0, stream>>>(x, n1w, n1b, H8);
  gemm8<E8_BF16><<<dim3(3072 / 128, NTOK / 128), dim3(256), 0, stream>>>(
      H8, W8QKV, (float*)(ws + OFF_BSAQKV), QKV, nullptr, nullptr, nullptr, nullptr,
      NTOK, 3072, 1024, 1);
  {
    Rope2 r;
    r.j[0] = {QKV, QR, 3072, 0,    LQ, NTOK, QSCALE};
    r.j[1] = {QKV, KR, 3072, 1024, LQ, NTOK, 1.0f};
    rope2<<<dim3(NTOK, 2), dim3(128), 0, stream>>>(r, tcos, tsin);
  }
  vtrans<<<dim3(LQ / 64, Bn * H), dim3(256), 0, stream>>>(QKV, 3072, 2048, VT, LQ);
  flash_attn2<1><<<dim3(512), dim3(256), 0, stream>>>(QR, KR, VT, AO8, LQ, LQ);
  gemm8<E8_RESID><<<dim3(1024 / 128, NTOK / 128), dim3(256), 0, stream>>>(
      AO8, W8SAP, sa_pb, nullptr, nullptr, out, x, g_msa, NTOK, 1024, 1024, 1);

  // ---- cross-attention ----
  ln_fp8<<<dim3(NTOK), dim3(256), 0, stream>>>(out, n2w, n2b, H8);
  gemm8<E8_BF16><<<dim3(1024 / 128, NTOK / 128), dim3(256), 0, stream>>>(
      H8, W8CAQ, ca_qb, (u16*)(ws + OFF_CAQ), nullptr, nullptr, nullptr, nullptr,
      NTOK, 1024, 1024, 1);
  gemm8<E8_BF16><<<dim3(2048 / 128, NCTX / 128), dim3(256), 0, stream>>>(
      CTX8, W8CAKV, (float*)(ws + OFF_BCAKV), (u16*)(ws + OFF_CAKV), nullptr, nullptr,
      nullptr, nullptr, NCTX, 2048, 1024, 1);
  {
    Rope2 r;
    r.j[0] = {(u16*)(ws + OFF_CAQ),  QR, 1024, 0, LQ, NTOK, QSCALE};
    r.j[1] = {(u16*)(ws + OFF_CAKV), KR, 2048, 0, LC, NCTX, 1.0f};
    rope2<<<dim3(NTOK, 2), dim3(128), 0, stream>>>(r, tcos, tsin);
  }
  vtrans<<<dim3(LC / 64, Bn * H), dim3(256), 0, stream>>>(
      (u16*)(ws + OFF_CAKV), 2048, 1024, VT, LC);
  flash_attn2<0><<<dim3(512), dim3(256), 0, stream>>>(QR, KR, VT, AO8, LQ, LC);
  gemm8<E8_RESID><<<dim3(1024 / 128, NTOK / 128), dim3(256), 0, stream>>>(
      AO8, W8CAP, ca_pb, nullptr, nullptr, out, out, g_ca, NTOK, 1024, 1024, 1);

  // ---- MLP (fp8 MX path) ----
  ln_fp8<<<dim3(NTOK), dim3(256), 0, stream>>>(out, n3w, n3b, H8);
  gemm8<E8_GELU><<<dim3(4096 / 128, NTOK / 128), dim3(256), 0, stream>>>(
      H8, W8FC1, fc1b, nullptr, U8, nullptr, nullptr, nullptr, NTOK, 4096, 1024, 1);
  // fc2: split-K x2 atomic via gemm8p (B-staged + A reg-prefetch); bias+gate pre-applied
  init_bias_gate<<<dim3(4096), dim3(256), 0, stream>>>(out, fc2b, g_mlp);
  gemm8p<E8_ATOMIC><<<dim3(1024 / 128, NTOK / 128, 2), dim3(256), 0, stream>>>(
      U8, W8FC2, nullptr, out, g_mlp, NTOK, 1024, 4096, 2);
}

// Round 19
// 312.812 us; speedup vs baseline: 1.2198x; 1.0404x over previous
//
#include <hip/hip_runtime.h>
#include <math.h>

#if !__has_builtin(__builtin_amdgcn_cvt_pk_fp8_f32)
#include <hip/hip_fp8.h>
#endif

typedef __attribute__((ext_vector_type(8))) short short8;
typedef __attribute__((ext_vector_type(4))) float f32x4;
typedef __attribute__((ext_vector_type(16))) float f32x16;
typedef unsigned char u8;
typedef unsigned short u16;
typedef unsigned int u32;
typedef __attribute__((ext_vector_type(2))) u32 u32x2;
typedef __attribute__((ext_vector_type(4))) u32 u32x4;
typedef __attribute__((ext_vector_type(8))) int i32x8;
typedef unsigned long long u64;

static constexpr int E = 1024, H = 16, LQ = 1024, LC = 512, Bn = 4, FF = 4096;
static constexpr int NTOK = Bn * LQ;   // 4096
static constexpr int NCTX = Bn * LC;   // 2048

#define QSCALE 0.1803368801111244f
#define DEFER_THR 11.5f
#define AOSCL 16.0f

// ---------------- workspace layout (bytes) ----------------
static constexpr size_t OFF_TCOS   = 0;
static constexpr size_t OFF_TSIN   = OFF_TCOS + (size_t)LQ*32*4;
static constexpr size_t OFF_BSAQKV = OFF_TSIN + (size_t)LQ*32*4;
static constexpr size_t OFF_BCAKV  = OFF_BSAQKV + 16384;
static constexpr size_t OFF_W8     = OFF_BCAKV + 16384;
static constexpr size_t OFF_W8QKV  = OFF_W8;                               // [3072][1024]
static constexpr size_t OFF_W8SAP  = OFF_W8QKV  + (size_t)3*1048576;
static constexpr size_t OFF_W8CAQ  = OFF_W8SAP  + (size_t)1*1048576;
static constexpr size_t OFF_W8CAKV = OFF_W8CAQ  + (size_t)1*1048576;
static constexpr size_t OFF_W8CAP  = OFF_W8CAKV + (size_t)2*1048576;
static constexpr size_t OFF_W8FC1  = OFF_W8CAP  + (size_t)1*1048576;
static constexpr size_t OFF_W8FC2  = OFF_W8FC1  + (size_t)4*1048576;
static constexpr size_t OFF_CTX8   = OFF_W8FC2  + (size_t)4*1048576;
static constexpr size_t OFF_CTXB   = OFF_W8 + (size_t)30*1048576 + (size_t)2048*1024*2;
static constexpr size_t OFF_H      = OFF_CTXB   + (size_t)2048*1024*2;
static constexpr size_t OFF_QKV    = OFF_H      + (size_t)4096*1024*2;
static constexpr size_t OFF_CAQ    = OFF_QKV;
static constexpr size_t OFF_CAKV   = OFF_QKV + (size_t)4096*1024*2;
static constexpr size_t OFF_QR     = OFF_QKV + (size_t)4096*3072*2;
static constexpr size_t OFF_KR     = OFF_QR  + (size_t)4096*1024*2;
static constexpr size_t OFF_VT     = OFF_KR  + (size_t)4096*1024*2;
static constexpr size_t OFF_AO     = OFF_VT  + (size_t)4096*1024*2;
static constexpr size_t OFF_U      = OFF_QKV;
static constexpr size_t WS_NEED    = OFF_AO + (size_t)4096*1024*2;

// ---------------- helpers ----------------
static __device__ __forceinline__ float bf2f(u16 u) {
  union { u32 i; float f; } un; un.i = ((u32)u) << 16; return un.f;
}
static __device__ __forceinline__ u16 f2bf(float f) {  // RNE
  union { float f; u32 u; } un; un.f = f;
  u32 u = un.u;
  return (u16)((u + 0x7FFFu + ((u >> 16) & 1u)) >> 16);
}
static __device__ __forceinline__ u64 pack4(u16 a, u16 b, u16 c, u16 d) {
  return (u64)a | ((u64)b << 16) | ((u64)c << 32) | ((u64)d << 48);
}
static __device__ __forceinline__ f32x16 mfma32(short8 a, short8 b, f32x16 c) {
  return __builtin_amdgcn_mfma_f32_32x32x16_bf16(a, b, c, 0, 0, 0);
}
static __device__ __forceinline__ void gload_lds16(void* lds, const void* g) {
  __builtin_amdgcn_global_load_lds(
      (const __attribute__((address_space(1))) void*)g,
      (__attribute__((address_space(3))) void*)lds, 16, 0, 0);
}
static __device__ __forceinline__ float gelu_tanh(float x) {
  float z2 = 1.5957691216057308f * (x + 0.044715f * x * x * x);
  float e = __expf(z2);
  float r = __builtin_amdgcn_rcpf(e + 1.0f);
  return x - x * r;
}
static __device__ __forceinline__ u32 cvtpk_bf16(float lo, float hi) {
  u32 r;
  asm("v_cvt_pk_bf16_f32 %0, %1, %2" : "=v"(r) : "v"(lo), "v"(hi));
  return r;
}
static __device__ __forceinline__ u32 pack_fp8x4(float a, float b, float c, float d) {
#if __has_builtin(__builtin_amdgcn_cvt_pk_fp8_f32)
  u32 r = (u32)__builtin_amdgcn_cvt_pk_fp8_f32(a, b, 0, false);
  r = (u32)__builtin_amdgcn_cvt_pk_fp8_f32(c, d, (int)r, true);
  return r;
#else
  __hip_fp8_e4m3 qa(a), qb(b), qc(c), qd(d);
  return (u32)qa.__x | ((u32)qb.__x << 8) | ((u32)qc.__x << 16) | ((u32)qd.__x << 24);
#endif
}
static __device__ __forceinline__ u8 fp8b(float f) {
#if __has_builtin(__builtin_amdgcn_cvt_pk_fp8_f32)
  return (u8)((u32)__builtin_amdgcn_cvt_pk_fp8_f32(f, f, 0, false) & 0xFFu);
#else
  __hip_fp8_e4m3 t(f); return t.__x;
#endif
}

// ---------------- small kernels ----------------
__global__ __launch_bounds__(256) void build_tab(float* __restrict__ ct, float* __restrict__ st) {
  int idx = blockIdx.x * 256 + threadIdx.x;
  int pos = idx >> 5, i = idx & 31;
  float inv = powf(10000.f, -(float)i * (1.f / 32.f));
  float a = (float)pos * inv;
  ct[idx] = cosf(a);
  st[idx] = sinf(a);
}

struct CvtF8 { const float* s[10]; };
__global__ __launch_bounds__(256) void cvt_fp8c(CvtF8 a, const float* __restrict__ ctx,
                                                u8* __restrict__ dst) {
  u32 gid = blockIdx.x * 256 + threadIdx.x;
  u32 seg = gid >> 18, off = gid & 262143u;
  const float* s;
  float scl = 256.f;
  if (seg < 8)       s = a.s[seg];
  else if (seg < 12) s = a.s[8] + (size_t)(seg - 8) * 1048576;
  else if (seg < 16) s = a.s[9] + (size_t)(seg - 12) * 1048576;
  else             { s = ctx + (size_t)(seg - 16) * 1048576; scl = 16.f; }
  float4 v = *(const float4*)(s + (size_t)off * 4);
  *(u32*)(dst + (size_t)seg * 1048576 + (size_t)off * 4) =
      pack_fp8x4(v.x * scl, v.y * scl, v.z * scl, v.w * scl);
}

struct Cp5 { const float* s[5]; };
__global__ __launch_bounds__(256) void copy5(Cp5 a, float* __restrict__ dst) {
  int gid = blockIdx.x * 256 + threadIdx.x;
  int s = gid >> 10, off = gid & 1023;
  int doff = (s < 3) ? s * 1024 : 4096 + (s - 3) * 1024;
  dst[doff + off] = a.s[s][off];
}

__global__ __launch_bounds__(256) void init_bias_gate(float* __restrict__ out, const float* __restrict__ bias,
                                                      const float* __restrict__ gate) {
  int i = (blockIdx.x * 256 + threadIdx.x) * 4;
  int c = i & 1023;
  float4 o = *(float4*)(out + i);
  o.x += gate[c] * bias[c];
  o.y += gate[c + 1] * bias[c + 1];
  o.z += gate[c + 2] * bias[c + 2];
  o.w += gate[c + 3] * bias[c + 3];
  *(float4*)(out + i) = o;
}

__global__ __launch_bounds__(256) void ln_fp8(const float* __restrict__ x, const float* __restrict__ w,
                                              const float* __restrict__ b, u8* __restrict__ out) {
  __shared__ float red[4];
  int row = blockIdx.x, tid = threadIdx.x;
  const float* xr = x + (size_t)row * 1024;
  float4 v = ((const float4*)xr)[tid];
  float s = v.x + v.y + v.z + v.w;
#pragma unroll
  for (int off = 32; off; off >>= 1) s += __shfl_xor(s, off);
  if ((tid & 63) == 0) red[tid >> 6] = s;
  __syncthreads();
  float mean = (red[0] + red[1] + red[2] + red[3]) * (1.f / 1024.f);
  float dx = v.x - mean, dy = v.y - mean, dz = v.z - mean, dw = v.w - mean;
  float sq = dx * dx + dy * dy + dz * dz + dw * dw;
#pragma unroll
  for (int off = 32; off; off >>= 1) sq += __shfl_xor(sq, off);
  __syncthreads();
  if ((tid & 63) == 0) red[tid >> 6] = sq;
  __syncthreads();
  float var = (red[0] + red[1] + red[2] + red[3]) * (1.f / 1024.f);
  float rstd = rsqrtf(var + 1e-6f);
  float4 wv = ((const float4*)w)[tid];
  float4 bv = ((const float4*)b)[tid];
  u32 pk = pack_fp8x4((dx * rstd * wv.x + bv.x) * 16.f, (dy * rstd * wv.y + bv.y) * 16.f,
                      (dz * rstd * wv.z + bv.z) * 16.f, (dw * rstd * wv.w + bv.w) * 16.f);
  *(u32*)(out + (size_t)row * 1024 + tid * 4) = pk;
}

struct RopeJob { const u16* src; u16* dst; int ld, col0, Lper, T; float scale; };
struct Rope2 { RopeJob j[2]; };
__global__ __launch_bounds__(128) void rope2(Rope2 a, const float* __restrict__ cosT,
                                             const float* __restrict__ sinT) {
  RopeJob jb = a.j[blockIdx.y];
  int t = blockIdx.x;
  if (t >= jb.T) return;
  int b = t / jb.Lper, l = t - b * jb.Lper;
  int tid = threadIdx.x;
  int e0 = tid * 8;
  int h = e0 >> 6, d0 = e0 & 63;
  short8 vv = *(const short8*)(jb.src + (size_t)t * jb.ld + jb.col0 + e0);
  short8 ov;
#pragma unroll
  for (int j = 0; j < 4; ++j) {
    float x1 = bf2f((u16)vv[2 * j]);
    float x2 = bf2f((u16)vv[2 * j + 1]);
    int i = (d0 >> 1) + j;
    float c = cosT[l * 32 + i], s = sinT[l * 32 + i];
    ov[2 * j]     = (short)f2bf((x1 * c - x2 * s) * jb.scale);
    ov[2 * j + 1] = (short)f2bf((x1 * s + x2 * c) * jb.scale);
  }
  *(short8*)(jb.dst + (((size_t)b * H + h) * jb.Lper + l) * 64 + d0) = ov;
}

__global__ __launch_bounds__(256) void vtrans(const u16* __restrict__ src, int ld, int col0,
                                              u16* __restrict__ dst, int Lper) {
  __shared__ u16 tile[64][72];
  int bh = blockIdx.y;
  int b = bh >> 4, h = bh & 15;
  int l0 = blockIdx.x * 64;
  int tid = threadIdx.x;
#pragma unroll
  for (int j = 0; j < 2; ++j) {
    int c = tid + j * 256;
    int i = c >> 3, d0 = (c & 7) * 8;
    short8 v = *(const short8*)(src + (size_t)(b * Lper + l0 + i) * ld + col0 + h * 64 + d0);
    *(short8*)(&tile[i][d0]) = v;
  }
  __syncthreads();
#pragma unroll
  for (int j = 0; j < 2; ++j) {
    int c = tid + j * 256;
    int d = c >> 3, lc = (c & 7) * 8;
    short8 v;
#pragma unroll
    for (int k = 0; k < 8; ++k) v[k] = (short)tile[lc + k][d];
    *(short8*)(dst + (((size_t)bh) * 64 + d) * Lper + l0 + lc) = v;
  }
}

// ---------------- fp8 MX GEMM (R16-proven): A+B LDS-staged, 2 blocks/CU ----------------
enum { E8_BF16 = 0, E8_GELU = 1, E8_ATOMIC = 2, E8_RESID = 3 };

template <int EPI>
__global__ __launch_bounds__(256, 2) void gemm8(const u8* __restrict__ A, const u8* __restrict__ W,
                                                const float* __restrict__ bias, u16* outb16,
                                                u8* outb8, float* outf, const float* res,
                                                const float* __restrict__ gate,
                                                int M, int N, int K, int kchunks) {
  __shared__ u8 As[2][128 * 128];
  __shared__ u8 Bs[2][128 * 128];

  int nwg = gridDim.x * gridDim.y;
  int bid = blockIdx.y * gridDim.x + blockIdx.x;
  int cpx = nwg >> 3;
  int swz = (bid & 7) * cpx + (bid >> 3);
  int bx = swz % gridDim.x, by = swz / gridDim.x;
  int row0 = by * 128, col0 = bx * 128;

  const int Kc = K / kchunks;
  const int kbase = blockIdx.z * Kc;

  int tid = threadIdx.x;
  int lane = tid & 63, wid = tid >> 6;
  int wr = wid >> 1, wc = wid & 1;
  int lr = lane & 15, lg = lane >> 4;

  u32 aoff[4], boff[4];
  int ldso[4];
#pragma unroll
  for (int j = 0; j < 4; ++j) {
    int q = tid + j * 256;
    int r = q >> 3, p = q & 7, sp = p ^ (r & 7);
    aoff[j] = (u32)(row0 + r) * (u32)K + sp * 16;
    boff[j] = (u32)(col0 + r) * (u32)K + sp * 16;
    ldso[j] = q * 16;
  }

  f32x4 acc[4][4] = {};
  const int nkt = Kc >> 7;

  auto rdfrag = [&](const u8* base, int r, i32x8& f) {
    const u8* rp = base + r * 128;
    int ck = lg * 2;
    u32x4 lo = *(const u32x4*)(rp + ((ck) ^ (r & 7)) * 16);
    u32x4 hh = *(const u32x4*)(rp + ((ck + 1) ^ (r & 7)) * 16);
    i32x8 v;
    v[0] = (int)lo[0]; v[1] = (int)lo[1]; v[2] = (int)lo[2]; v[3] = (int)lo[3];
    v[4] = (int)hh[0]; v[5] = (int)hh[1]; v[6] = (int)hh[2]; v[7] = (int)hh[3];
    f = v;
  };

#pragma unroll
  for (int j = 0; j < 4; ++j) {
    gload_lds16(&As[0][ldso[j]], A + aoff[j] + kbase);
    gload_lds16(&Bs[0][ldso[j]], W + boff[j] + kbase);
  }
  __syncthreads();

  for (int kt = 0; kt < nkt; ++kt) {
    int cur = kt & 1;
    if (kt + 1 < nkt) {
      int k0 = kbase + ((kt + 1) << 7);
#pragma unroll
      for (int j = 0; j < 4; ++j) {
        gload_lds16(&As[cur ^ 1][ldso[j]], A + aoff[j] + k0);
        gload_lds16(&Bs[cur ^ 1][ldso[j]], W + boff[j] + k0);
      }
    }
    i32x8 a[4], b[4];
#pragma unroll
    for (int m = 0; m < 4; ++m) rdfrag(&As[cur][0], wr * 64 + m * 16 + lr, a[m]);
#pragma unroll
    for (int n = 0; n < 4; ++n) rdfrag(&Bs[cur][0], wc * 64 + n * 16 + lr, b[n]);
    __builtin_amdgcn_s_setprio(1);
#pragma unroll
    for (int m = 0; m < 4; ++m)
#pragma unroll
      for (int n = 0; n < 4; ++n)
        acc[m][n] = __builtin_amdgcn_mfma_scale_f32_16x16x128_f8f6f4(
            a[m], b[n], acc[m][n], 0, 0, 0, 0x7F7F7F7F, 0, 0x7F7F7F7F);
    __builtin_amdgcn_s_setprio(0);
    __syncthreads();
  }

  constexpr float SCL = 1.f / 4096.f;
  if (EPI == E8_BF16) {
    u16* Ct = (u16*)&As[0][0];
#pragma unroll
    for (int n = 0; n < 4; ++n) {
      int cl = wc * 64 + n * 16 + lr;
      float bv = bias[col0 + cl];
#pragma unroll
      for (int m = 0; m < 4; ++m) {
#pragma unroll
        for (int i = 0; i < 4; ++i) {
          int rl = wr * 64 + m * 16 + lg * 4 + i;
          Ct[rl * 128 + cl] = f2bf(acc[m][n][i] * SCL + bv);
        }
      }
    }
    __syncthreads();
#pragma unroll
    for (int j = 0; j < 8; ++j) {
      u32 q = (u32)tid + j * 256;
      u32 r = q >> 4, ck = q & 15;
      short8 v = *(const short8*)(Ct + r * 128 + ck * 8);
      *(short8*)(outb16 + (size_t)(row0 + r) * N + col0 + ck * 8) = v;
    }
  } else if (EPI == E8_GELU) {
    u8* Ct = &As[0][0];
#pragma unroll
    for (int n = 0; n < 4; ++n) {
      int cl = wc * 64 + n * 16 + lr;
      float bv = bias[col0 + cl];
#pragma unroll
      for (int m = 0; m < 4; ++m) {
#pragma unroll
        for (int i = 0; i < 4; ++i) {
          int rl = wr * 64 + m * 16 + lg * 4 + i;
          float v = acc[m][n][i] * SCL + bv;
          Ct[rl * 128 + cl] = fp8b(gelu_tanh(v) * 16.f);
        }
      }
    }
    __syncthreads();
#pragma unroll
    for (int j = 0; j < 4; ++j) {
      int q = tid + j * 256;
      int r = q >> 3, ck = q & 7;
      *(u32x4*)(outb8 + (size_t)(row0 + r) * N + col0 + ck * 16) =
          *(const u32x4*)(Ct + r * 128 + ck * 16);
    }
  } else if (EPI == E8_RESID) {
#pragma unroll
    for (int n = 0; n < 4; ++n) {
      int cg = col0 + wc * 64 + n * 16 + lr;
      float bv = bias[cg], gv = gate[cg];
#pragma unroll
      for (int m = 0; m < 4; ++m) {
#pragma unroll
        for (int i = 0; i < 4; ++i) {
          int rg = row0 + wr * 64 + m * 16 + lg * 4 + i;
          float v = acc[m][n][i] * SCL + bv;
          float r = res[(size_t)rg * N + cg];
          outf[(size_t)rg * N + cg] = r + gv * v;
        }
      }
    }
  } else {
#pragma unroll
    for (int n = 0; n < 4; ++n) {
      int cg = col0 + wc * 64 + n * 16 + lr;
      float gv = gate[cg];
#pragma unroll
      for (int m = 0; m < 4; ++m) {
#pragma unroll
        for (int i = 0; i < 4; ++i) {
          int rg = row0 + wr * 64 + m * 16 + lg * 4 + i;
          atomicAdd(&outf[(size_t)rg * N + cg], gv * (acc[m][n][i] * SCL));
        }
      }
    }
  }
}

// ---------------- flash attention, swapped-QK^T, register-pipelined K/V ----------------
template <int MASKED, int PRE>
static __device__ __forceinline__ void attn_tile3(short8* kf, const u16* KtNext,
                                                  const u16* Vp0, const u16* Vp1,
                                                  const short8* qf, int kb, int q0, int l31, int hi,
                                                  float& m, float& lsum, f32x16& o0, f32x16& o1) {
  short8 vf0[4], vf1[4];
#pragma unroll
  for (int ks = 0; ks < 4; ++ks) {
    vf0[ks] = *(const short8*)(Vp0 + ks * 16 + hi * 8);
    vf1[ks] = *(const short8*)(Vp1 + ks * 16 + hi * 8);
  }
  f32x16 s0 = {}, s1 = {};
  __builtin_amdgcn_s_setprio(1);
#pragma unroll
  for (int s = 0; s < 4; ++s) {
    s0 = mfma32(kf[s], qf[s], s0);
    s1 = mfma32(kf[4 + s], qf[s], s1);
  }
  __builtin_amdgcn_s_setprio(0);
  if (PRE) {
    const u16* kp0 = KtNext + (size_t)l31 * 64 + hi * 8;
    const u16* kp1 = KtNext + (size_t)(32 + l31) * 64 + hi * 8;
#pragma unroll
    for (int s = 0; s < 4; ++s) {
      kf[s] = *(const short8*)(kp0 + s * 16);
      kf[4 + s] = *(const short8*)(kp1 + s * 16);
    }
  }
  if (MASKED) {
    int qg = q0 + l31;
#pragma unroll
    for (int r = 0; r < 16; ++r) {
      int kk = kb + (r & 3) + 8 * (r >> 2) + 4 * hi;
      if (kk > qg) s0[r] = -INFINITY;
      if (kk + 32 > qg) s1[r] = -INFINITY;
    }
  }
  float pm = -INFINITY;
#pragma unroll
  for (int r = 0; r < 16; ++r) pm = fmaxf(pm, fmaxf(s0[r], s1[r]));
  pm = fmaxf(pm, __shfl_xor(pm, 32));
  if (!__all(pm <= m + DEFER_THR)) {
    float mn = fmaxf(m, pm);
    float al = exp2f(m - mn);
    m = mn;
    lsum *= al;
#pragma unroll
    for (int r = 0; r < 16; ++r) {
      float alr = __shfl(al, (r & 3) + 8 * (r >> 2) + 4 * hi);
      o0[r] *= alr;
      o1[r] *= alr;
    }
  }
  float ts = 0.f;
#pragma unroll
  for (int r = 0; r < 16; ++r) {
    float p0 = exp2f(s0[r] - m);
    float p1 = exp2f(s1[r] - m);
    s0[r] = p0; s1[r] = p1;
    ts += p0 + p1;
  }
  ts += __shfl_xor(ts, 32);
  lsum += ts;
  auto pack8 = [&](float a0, float a1, float a2, float a3,
                   float a4, float a5, float a6, float a7) -> short8 {
    u32 c0 = cvtpk_bf16(a0, a1), c1 = cvtpk_bf16(a2, a3);
    u32 c2 = cvtpk_bf16(a4, a5), c3 = cvtpk_bf16(a6, a7);
    u32x2 r02 = __builtin_amdgcn_permlane32_swap(c0, c2, false, false);
    u32x2 r13 = __builtin_amdgcn_permlane32_swap(c1, c3, false, false);
    u32x4 w;
    w[0] = r02[0]; w[1] = r13[0]; w[2] = r02[1]; w[3] = r13[1];
    return __builtin_bit_cast(short8, w);
  };
  short8 pa0 = pack8(s0[0], s0[1], s0[2], s0[3], s0[4], s0[5], s0[6], s0[7]);
  short8 pa1 = pack8(s0[8], s0[9], s0[10], s0[11], s0[12], s0[13], s0[14], s0[15]);
  short8 pa2 = pack8(s1[0], s1[1], s1[2], s1[3], s1[4], s1[5], s1[6], s1[7]);
  short8 pa3 = pack8(s1[8], s1[9], s1[10], s1[11], s1[12], s1[13], s1[14], s1[15]);
  short8 pa[4] = {pa0, pa1, pa2, pa3};
  __builtin_amdgcn_s_setprio(1);
#pragma unroll
  for (int ks = 0; ks < 4; ++ks) {
    o0 = mfma32(pa[ks], vf0[ks], o0);
    o1 = mfma32(pa[ks], vf1[ks], o1);
  }
  __builtin_amdgcn_s_setprio(0);
}

template <int CAUSAL>
__global__ __launch_bounds__(256) void flash_attn2(const u16* __restrict__ Q, const u16* __restrict__ K,
                                                   const u16* __restrict__ Vt, u8* __restrict__ O,
                                                   int Lq, int Lk) {
  const int wid = threadIdx.x >> 6, lane = threadIdx.x & 63;
  const int l31 = lane & 31, hi = lane >> 5;
  int wg = blockIdx.x * 4 + wid;
  int bh = wg & 63;
  int qc = wg >> 6;
  if (CAUSAL) qc = (Lq >> 5) - 1 - qc;
  int q0 = qc << 5;

  const u16* Qb = Q + ((size_t)bh * Lq + q0) * 64;
  const u16* Kb = K + (size_t)bh * Lk * 64;
  const u16* Vb = Vt + (size_t)bh * 64 * Lk;

  short8 qf[4];
#pragma unroll
  for (int s = 0; s < 4; ++s) qf[s] = *(const short8*)(Qb + (size_t)l31 * 64 + s * 16 + hi * 8);

  f32x16 o0 = {}, o1 = {};
  float m = -INFINITY, lsum = 0.f;

  const u16* Kt = Kb;
  const u16* Vp0 = Vb + (size_t)l31 * Lk;
  const u16* Vp1 = Vb + (size_t)(32 + l31) * Lk;

  short8 kf[8];
  {
    const u16* kp0 = Kt + (size_t)l31 * 64 + hi * 8;
    const u16* kp1 = Kt + (size_t)(32 + l31) * 64 + hi * 8;
#pragma unroll
    for (int s = 0; s < 4; ++s) {
      kf[s] = *(const short8*)(kp0 + s * 16);
      kf[4 + s] = *(const short8*)(kp1 + s * 16);
    }
  }

  int nt = CAUSAL ? ((q0 >> 6) + 1) : (Lk >> 6);
  for (int t = 0; t < nt - 1; ++t) {
    attn_tile3<0, 1>(kf, Kt + 64 * 64, Vp0, Vp1, qf, t * 64, q0, l31, hi, m, lsum, o0, o1);
    Kt += 64 * 64; Vp0 += 64; Vp1 += 64;
  }
  if (CAUSAL)
    attn_tile3<1, 0>(kf, nullptr, Vp0, Vp1, qf, (nt - 1) * 64, q0, l31, hi, m, lsum, o0, o1);
  else
    attn_tile3<0, 0>(kf, nullptr, Vp0, Vp1, qf, (nt - 1) * 64, q0, l31, hi, m, lsum, o0, o1);

  float myinv = AOSCL / lsum;
  int b = bh >> 4, h = bh & 15;
#pragma unroll
  for (int r = 0; r < 16; ++r) {
    int cr = (r & 3) + 8 * (r >> 2) + 4 * hi;
    float li = __shfl(myinv, cr);
    u8* op = O + ((size_t)b * Lq + q0 + cr) * 1024 + h * 64;
    op[l31] = fp8b(o0[r] * li);
    op[32 + l31] = fp8b(o1[r] * li);
  }
}

// ---------------- launch ----------------
extern "C" void kernel_launch(void* const* d_in, const int* in_sizes, int n_in,
                              void* d_out, int out_size, void* d_ws, size_t ws_size,
                              hipStream_t stream) {
  (void)in_sizes; (void)n_in; (void)out_size;
  if (ws_size < WS_NEED) return;

  const float* x     = (const float*)d_in[0];
  const float* ctx   = (const float*)d_in[1];
  const float* g_msa = (const float*)d_in[3];
  const float* g_ca  = (const float*)d_in[4];
  const float* g_mlp = (const float*)d_in[5];
  const float* n1w = (const float*)d_in[6],  *n1b = (const float*)d_in[7];
  const float* n2w = (const float*)d_in[8],  *n2b = (const float*)d_in[9];
  const float* n3w = (const float*)d_in[10], *n3b = (const float*)d_in[11];
  const float* sa_qw = (const float*)d_in[12], *sa_kw = (const float*)d_in[14];
  const float* sa_vw = (const float*)d_in[16], *sa_pw = (const float*)d_in[18];
  const float* sa_qb = (const float*)d_in[13], *sa_kb = (const float*)d_in[15];
  const float* sa_vb = (const float*)d_in[17], *sa_pb = (const float*)d_in[19];
  const float* ca_qw = (const float*)d_in[20], *ca_qb = (const float*)d_in[21];
  const float* ca_kw = (const float*)d_in[22], *ca_kb = (const float*)d_in[23];
  const float* ca_vw = (const float*)d_in[24], *ca_vb = (const float*)d_in[25];
  const float* ca_pw = (const float*)d_in[26], *ca_pb = (const float*)d_in[27];
  const float* fc1w = (const float*)d_in[28], *fc1b = (const float*)d_in[29];
  const float* fc2w = (const float*)d_in[30], *fc2b = (const float*)d_in[31];

  char* ws = (char*)d_ws;
  float* out = (float*)d_out;
  float* tcos = (float*)(ws + OFF_TCOS);
  float* tsin = (float*)(ws + OFF_TSIN);
  u16* QKV  = (u16*)(ws + OFF_QKV);
  u16* QR   = (u16*)(ws + OFF_QR);
  u16* KR   = (u16*)(ws + OFF_KR);
  u16* VT   = (u16*)(ws + OFF_VT);
  u8*  AO8  = (u8*)(ws + OFF_AO);
  u8*  H8   = (u8*)(ws + OFF_H);
  u8*  U8   = (u8*)(ws + OFF_U);
  u8*  W8QKV  = (u8*)(ws + OFF_W8QKV);
  u8*  W8SAP  = (u8*)(ws + OFF_W8SAP);
  u8*  W8CAQ  = (u8*)(ws + OFF_W8CAQ);
  u8*  W8CAKV = (u8*)(ws + OFF_W8CAKV);
  u8*  W8CAP  = (u8*)(ws + OFF_W8CAP);
  u8*  W8FC1  = (u8*)(ws + OFF_W8FC1);
  u8*  W8FC2  = (u8*)(ws + OFF_W8FC2);
  u8*  CTX8   = (u8*)(ws + OFF_CTX8);

  build_tab<<<dim3(128), dim3(256), 0, stream>>>(tcos, tsin);
  CvtF8 cf;
  cf.s[0] = sa_qw; cf.s[1] = sa_kw; cf.s[2] = sa_vw; cf.s[3] = sa_pw;
  cf.s[4] = ca_qw; cf.s[5] = ca_kw; cf.s[6] = ca_vw; cf.s[7] = ca_pw;
  cf.s[8] = fc1w;  cf.s[9] = fc2w;
  cvt_fp8c<<<dim3(18432), dim3(256), 0, stream>>>(cf, ctx, W8QKV);
  Cp5 cp;
  cp.s[0] = sa_qb; cp.s[1] = sa_kb; cp.s[2] = sa_vb; cp.s[3] = ca_kb; cp.s[4] = ca_vb;
  copy5<<<dim3(20), dim3(256), 0, stream>>>(cp, (float*)(ws + OFF_BSAQKV));

  // ---- self-attention ----
  ln_fp8<<<dim3(NTOK), dim3(256), 0, stream>>>(x, n1w, n1b, H8);
  gemm8<E8_BF16><<<dim3(3072 / 128, NTOK / 128), dim3(256), 0, stream>>>(
      H8, W8QKV, (float*)(ws + OFF_BSAQKV), QKV, nullptr, nullptr, nullptr, nullptr,
      NTOK, 3072, 1024, 1);
  {
    Rope2 r;
    r.j[0] = {QKV, QR, 3072, 0,    LQ, NTOK, QSCALE};
    r.j[1] = {QKV, KR, 3072, 1024, LQ, NTOK, 1.0f};
    rope2<<<dim3(NTOK, 2), dim3(128), 0, stream>>>(r, tcos, tsin);
  }
  vtrans<<<dim3(LQ / 64, Bn * H), dim3(256), 0, stream>>>(QKV, 3072, 2048, VT, LQ);
  flash_attn2<1><<<dim3(512), dim3(256), 0, stream>>>(QR, KR, VT, AO8, LQ, LQ);
  gemm8<E8_RESID><<<dim3(1024 / 128, NTOK / 128), dim3(256), 0, stream>>>(
      AO8, W8SAP, sa_pb, nullptr, nullptr, out, x, g_msa, NTOK, 1024, 1024, 1);

  // ---- cross-attention ----
  ln_fp8<<<dim3(NTOK), dim3(256), 0, stream>>>(out, n2w, n2b, H8);
  gemm8<E8_BF16><<<dim3(1024 / 128, NTOK / 128), dim3(256), 0, stream>>>(
      H8, W8CAQ, ca_qb, (u16*)(ws + OFF_CAQ), nullptr, nullptr, nullptr, nullptr,
      NTOK, 1024, 1024, 1);
  gemm8<E8_BF16><<<dim3(2048 / 128, NCTX / 128), dim3(256), 0, stream>>>(
      CTX8, W8CAKV, (float*)(ws + OFF_BCAKV), (u16*)(ws + OFF_CAKV), nullptr, nullptr,
      nullptr, nullptr, NCTX, 2048, 1024, 1);
  {
    Rope2 r;
    r.j[0] = {(u16*)(ws + OFF_CAQ),  QR, 1024, 0, LQ, NTOK, QSCALE};
    r.j[1] = {(u16*)(ws + OFF_CAKV), KR, 2048, 0, LC, NCTX, 1.0f};
    rope2<<<dim3(NTOK, 2), dim3(128), 0, stream>>>(r, tcos, tsin);
  }
  vtrans<<<dim3(LC / 64, Bn * H), dim3(256), 0, stream>>>(
      (u16*)(ws + OFF_CAKV), 2048, 1024, VT, LC);
  flash_attn2<0><<<dim3(512), dim3(256), 0, stream>>>(QR, KR, VT, AO8, LQ, LC);
  gemm8<E8_RESID><<<dim3(1024 / 128, NTOK / 128), dim3(256), 0, stream>>>(
      AO8, W8CAP, ca_pb, nullptr, nullptr, out, out, g_ca, NTOK, 1024, 1024, 1);

  // ---- MLP (fp8 MX path) ----
  ln_fp8<<<dim3(NTOK), dim3(256), 0, stream>>>(out, n3w, n3b, H8);
  gemm8<E8_GELU><<<dim3(4096 / 128, NTOK / 128), dim3(256), 0, stream>>>(
      H8, W8FC1, fc1b, nullptr, U8, nullptr, nullptr, nullptr, NTOK, 4096, 1024, 1);
  // fc2: split-K x2 atomic (512 blocks = 2/CU, R16-proven); bias+gate pre-applied
  init_bias_gate<<<dim3(4096), dim3(256), 0, stream>>>(out, fc2b, g_mlp);
  gemm8<E8_ATOMIC><<<dim3(1024 / 128, NTOK / 128, 2), dim3(256), 0, stream>>>(
      U8, W8FC2, nullptr, nullptr, nullptr, out, nullptr, g_mlp, NTOK, 1024, 4096, 2);
}